// Round 7
// baseline (482.045 us; speedup 1.0000x reference)
//
#include <hip/hip_runtime.h>
#include <math.h>

// Problem constants
#define B_    1024
#define IMG_  512
#define TXT_  300
#define NN_   14
#define FF_   2048
#define HID_  128
#define CC_   14
#define EE_   182
#define DD_   812
#define D3_   2436
#define BNR_  14336          // B_*NN_
#define KP_   832            // 812 padded to /32 (16B-aligned rows)
#define TXP_  320            // 300 padded to /32
#define AROWS_ 1152          // Aq/Ak/Av rows: 1024 data + 14 Tq + pad to tile mult

typedef __bf16 bf16x8 __attribute__((ext_vector_type(8)));
typedef float  f32x4  __attribute__((ext_vector_type(4)));
typedef unsigned short u16;
typedef unsigned short u16x4 __attribute__((ext_vector_type(4)));
typedef unsigned short u16x8 __attribute__((ext_vector_type(8)));

__device__ __forceinline__ u16 f2bf(float f) {
    union { float f; unsigned u; } v; v.f = f;
    unsigned r = v.u + 0x7FFFu + ((v.u >> 16) & 1u);   // RNE
    return (u16)(r >> 16);
}
__device__ __forceinline__ float bf2f(u16 h) {
    union { unsigned u; float f; } v; v.u = ((unsigned)h) << 16; return v.f;
}

// async global->LDS, 16B per lane. HW contract (m104/m108): LDS dst must be
// a WAVE-UNIFORM base; lane i's data lands at base + i*16. Global src is
// per-lane.
__device__ __forceinline__ void gload_lds16(const u16* g, u16* l) {
    __builtin_amdgcn_global_load_lds(
        (const __attribute__((address_space(1))) void*)g,
        (__attribute__((address_space(3))) void*)l, 16, 0, 0);
}

// ---------------------------------------------------------------------------
// Workspace layout (bytes), time-multiplexed overlays.
// ---------------------------------------------------------------------------
#define OFF_IMGB  0ULL              // bf16 [1024][512]
#define OFF_WIB   1048576ULL        // bf16 [2436][512]
#define OFF_WORDB 3543040ULL        // bf16 [128][320]
#define OFF_WITX  3624960ULL        // bf16 [2560][320]
#define OFF_GB    0ULL              // bf16 [14336][1024] (eG..P)
#define OFF_EBUF  29360128ULL       // f32  [1038][1024]  (S0..eG)
#define OFF_AVOT  33611776ULL       // bf16 [896][1024]   (mix2..P)
#define OFF_WOB   35446784ULL       // bf16 [896][832]    (mcast..mix2)
#define OFF_HB    0ULL              // bf16 [14336][2048] (FFN1..FFN2)
#define OFF_PB    58720256ULL       // bf16 [14336][812]  (P..ln1)
#define OFF_X1B   82001920ULL       // bf16 [14336][832]  (ln1..FFN2)
#define OFF_YB    105857024ULL      // bf16 [14336][832]  (FFN2..gcn)
#define OFF_W1T   129712128ULL      // bf16 [2048][832]   (mix2..FFN1)
#define OFF_W2T   133120000ULL      // bf16 [896][2048]   (mix2..FFN2)
#define OFF_AQB   152420352ULL      // bf16 3x[1152][832] (Aq|Ak|Av)
#define OFF_TVB   158307552ULL      // bf16 [128][832]
#define OFF_CO    158520544ULL      // f32  [14][812]
#define OFF_Z     158566016ULL      // f32  [14336]
#define OFF_ADJ   158623360ULL      // f32  [196 adj + 16 colw]
#define OFF_WG1T  158624384ULL      // bf16 [128][832]
#define OFF_WG2T  158837376ULL      // bf16 [128][128]

// ---------------------------------------------------------------------------
// epi 0: Cf=v. 1: Cb=bf16(relu(v+bias[cn])). 2: Cf=v+bias[cn]+bf2f(Cb).
// 3: Cb=bf16(v). 4: split-3 into [Aq|Ak|Av]. 5: Cb=bf16(v/bias[rm]).
// 6: Cf=v+bias[cn]. 7: Cb=bf16(v+bias[cn]+bf2f(((u16*)Cf)[rm*ldc+cn])).
// 8: T-split: cn<812 -> Cb[(1024+rm)*KP_+cn]; cn>=1624 -> ((u16*)Cf)[rm*KP_+cn-1624].
// ---------------------------------------------------------------------------
__device__ __forceinline__ void gemm_epi(
    float v, int rm, int cn, int epi,
    float* __restrict__ Cf, int ldc, u16* __restrict__ Cb, int ldcb,
    const float* __restrict__ bias)
{
    if (epi == 0) Cf[(size_t)rm * ldc + cn] = v;
    else if (epi == 1) { v += bias[cn]; v = v > 0.f ? v : 0.f;
                    Cb[(size_t)rm * ldcb + cn] = f2bf(v); }
    else if (epi == 2) Cf[(size_t)rm * ldc + cn] =
                    v + bias[cn] + bf2f(Cb[(size_t)rm * ldcb + cn]);
    else if (epi == 3) Cb[(size_t)rm * ldcb + cn] = f2bf(v);
    else if (epi == 4) { int bs = cn / DD_, cc = cn - bs * DD_;
                    Cb[(size_t)bs * (AROWS_ * KP_) + (size_t)rm * KP_ + cc] = f2bf(v); }
    else if (epi == 5) { float invz = 1.0f / bias[rm];
                    Cb[(size_t)rm * ldcb + cn] = f2bf(v * invz); }
    else if (epi == 6) Cf[(size_t)rm * ldc + cn] = v + bias[cn];
    else if (epi == 7) { const u16* rx = (const u16*)Cf;
                    Cb[(size_t)rm * ldcb + cn] =
                        f2bf(v + bias[cn] + bf2f(rx[(size_t)rm * ldc + cn])); }
    else if (epi == 8) {
        float t = v + bias[cn];
        if (cn < DD_) Cb[(size_t)(1024 + rm) * KP_ + cn] = f2bf(t);
        else if (cn >= 2 * DD_)
            ((u16*)Cf)[(size_t)rm * KP_ + (cn - 2 * DD_)] = f2bf(t);
    }
}

// ---------------------------------------------------------------------------
// 4-wave GEMM body: 128x128 tile, BK=32, 256 threads, 2x2 waves of 64x64,
// double-buffered global_load_lds, 32 KiB LDS -> 4 blocks/CU (register-capped
// at 120 regs/wave incl AGPR). T2 both-sides XOR swizzle (round-6; conflicts
// 6.4M -> 0, perf-neutral at this TLP — kept for free). Used for FFN1 and
// launch-5 where block count >> CU capacity (throughput regime).
// ---------------------------------------------------------------------------
__device__ __forceinline__ void gemm_body4(
    const u16* __restrict__ A, int lda,
    const u16* __restrict__ Bm, int ldb,
    int M, int N, int K, float scale,
    float* __restrict__ Cf, int ldc,
    u16* __restrict__ Cb, int ldcb,
    const float* __restrict__ bias,
    int nxt, int swiz, int epi, int id)
{
    __shared__ __align__(16) u16 As[2][128 * 32];
    __shared__ __align__(16) u16 Bs[2][128 * 32];
    const int tid = threadIdx.x;
    int bx, by;
    if (swiz) { int r8 = id & 7; int q = id >> 3; bx = q % nxt; by = (q / nxt) * 8 + r8; }
    else      { bx = id % nxt; by = id / nxt; }
    const int row0 = by * 128, col0 = bx * 128;
    const int lane = tid & 63, wv = tid >> 6;
    const int wm = (wv >> 1) * 64, wn = (wv & 1) * 64;
    const int fr = lane & 15, qd = lane >> 4;

    const int s_r0  = (wv * 64 + lane) >> 2;
    const int s_sw  = ((lane & 3) ^ ((lane >> 3) & 3)) * 8;   // swizzled src slot
    const int s_b0  = (wv * 64) * 8;
    const u16* Arow0 = A  + (size_t)(row0 + s_r0) * lda + s_sw;
    const u16* Arow1 = A  + (size_t)(row0 + s_r0 + 64) * lda + s_sw;
    const u16* Brow0 = Bm + (size_t)(col0 + s_r0) * ldb + s_sw;
    const u16* Brow1 = Bm + (size_t)(col0 + s_r0 + 64) * ldb + s_sw;
    const int qsw = (qd ^ ((fr >> 1) & 3)) * 8;               // swizzled read slot

    f32x4 acc[4][4] = {};

    const int T = K >> 5;
    gload_lds16(Arow0, &As[0][s_b0]);
    gload_lds16(Arow1, &As[0][s_b0 + 2048]);
    gload_lds16(Brow0, &Bs[0][s_b0]);
    gload_lds16(Brow1, &Bs[0][s_b0 + 2048]);

    for (int i = 0; i < T; ++i) {
        __syncthreads();
        const int cur = i & 1;
        if (i + 1 < T) {
            const int nb = cur ^ 1;
            const int ko = (i + 1) << 5;
            gload_lds16(Arow0 + ko, &As[nb][s_b0]);
            gload_lds16(Arow1 + ko, &As[nb][s_b0 + 2048]);
            gload_lds16(Brow0 + ko, &Bs[nb][s_b0]);
            gload_lds16(Brow1 + ko, &Bs[nb][s_b0 + 2048]);
        }
        bf16x8 af[4], bg[4];
        #pragma unroll
        for (int j = 0; j < 4; ++j) {
            af[j] = *(const bf16x8*)&As[cur][(wm + j * 16 + fr) * 32 + qsw];
            bg[j] = *(const bf16x8*)&Bs[cur][(wn + j * 16 + fr) * 32 + qsw];
        }
        #pragma unroll
        for (int mi = 0; mi < 4; ++mi)
            #pragma unroll
            for (int ni = 0; ni < 4; ++ni)
                acc[mi][ni] = __builtin_amdgcn_mfma_f32_16x16x32_bf16(
                    af[mi], bg[ni], acc[mi][ni], 0, 0, 0);
    }

    #pragma unroll
    for (int mi = 0; mi < 4; ++mi) {
        #pragma unroll
        for (int i = 0; i < 4; ++i) {
            int rm = row0 + wm + mi * 16 + qd * 4 + i;
            if (rm >= M) continue;
            #pragma unroll
            for (int ni = 0; ni < 4; ++ni) {
                int cn = col0 + wn + ni * 16 + fr;
                if (cn >= N) continue;
                gemm_epi(acc[mi][ni][i] * scale, rm, cn, epi, Cf, ldc, Cb, ldcb, bias);
            }
        }
    }
}

template<int EPI>
__global__ __launch_bounds__(256, 4)
void bgemm(const u16* __restrict__ A, int lda,
           const u16* __restrict__ Bm, int ldb,
           int M, int N, int K, float scale,
           float* __restrict__ Cf, int ldc,
           u16* __restrict__ Cb, int ldcb,
           const float* __restrict__ bias,
           int nxt, int swiz)
{
    gemm_body4(A, lda, Bm, ldb, M, N, K, scale, Cf, ldc, Cb, ldcb, bias,
               nxt, swiz, EPI, blockIdx.x);
}

// ---------------------------------------------------------------------------
// 256x256 phased GEMM body (round-3/5 measured: FFN2 ~95-97 µs, conflicts 0):
// 512 threads = 8 waves (2M x 4N), wave owns 128x64. BK=32, ring of FOUR
// K-tile LDS slots (128 KiB, 1 block/CU), counted-vmcnt. FFN2 only.
// ---------------------------------------------------------------------------
__device__ __forceinline__ void gemm256_body(
    const u16* __restrict__ A, int lda,
    const u16* __restrict__ Bm, int ldb,
    int M, int N, int K, float scale,
    float* __restrict__ Cf, int ldc,
    u16* __restrict__ Cb, int ldcb,
    const float* __restrict__ bias,
    int nxt, int epi, int id)
{
    __shared__ __align__(16) u16 As[4][8192];
    __shared__ __align__(16) u16 Bs[4][8192];
    const int tid = threadIdx.x;
    const int bx = id % nxt, by = id / nxt;
    const int row0 = by << 8, col0 = bx << 8;
    const int lane = tid & 63, wv = tid >> 6;
    const int wm = (wv >> 2) << 7;         // 0 / 128
    const int wn = (wv & 3) << 6;          // 0 / 64 / 128 / 192
    const int fr = lane & 15, qd = lane >> 4;

    // fragment LDS offsets (u16 units), read-side swizzle
    int aoff[8], boff[4];
    #pragma unroll
    for (int mi = 0; mi < 8; ++mi) {
        int r = wm + mi * 16 + fr;
        aoff[mi] = r * 32 + ((qd ^ ((r >> 1) & 3)) << 3);
    }
    #pragma unroll
    for (int ni = 0; ni < 4; ++ni) {
        int r = wn + ni * 16 + fr;
        boff[ni] = r * 32 + ((qd ^ ((r >> 1) & 3)) << 3);
    }

    // staging: chunk i (0..1023) -> linear LDS byte i*16; LDS base passed to
    // gload_lds is WAVE-UNIFORM (wv*512 u16); global source pre-swizzled so
    // linear LDS + swizzled read round-trips (rule #21).
    const int i0 = tid, i1 = 512 + tid;
    const int r0 = i0 >> 2, r1 = i1 >> 2;
    const int c0 = ((i0 & 3) ^ ((r0 >> 1) & 3)) << 3;
    const int c1 = ((i1 & 3) ^ ((r1 >> 1) & 3)) << 3;
    const u16* Ag0 = A  + (size_t)(row0 + r0) * lda + c0;
    const u16* Ag1 = A  + (size_t)(row0 + r1) * lda + c1;
    const u16* Bg0 = Bm + (size_t)(col0 + r0) * ldb + c0;
    const u16* Bg1 = Bm + (size_t)(col0 + r1) * ldb + c1;
    const int lb0 = wv * 512;                      // u16, wave-uniform
    const int lb1 = 4096 + wv * 512;               // u16, wave-uniform

    f32x4 acc[8][4] = {};
    const int T = K >> 5;                   // K multiple of 32, T >= 4

    // prologue: stage tiles 0,1,2 into slots 0,1,2
    #pragma unroll
    for (int p = 0; p < 3; ++p) {
        const int ko = p << 5;
        gload_lds16(Ag0 + ko, &As[p][lb0]);
        gload_lds16(Ag1 + ko, &As[p][lb1]);
        gload_lds16(Bg0 + ko, &Bs[p][lb0]);
        gload_lds16(Bg1 + ko, &Bs[p][lb1]);
    }
    __builtin_amdgcn_sched_barrier(0);
    asm volatile("s_waitcnt vmcnt(8)");            // tile 0 landed (this wave)
    __builtin_amdgcn_sched_barrier(0);
    __builtin_amdgcn_s_barrier();                  // ... in all waves
    __builtin_amdgcn_sched_barrier(0);

    for (int t = 0; t < T; ++t) {
        const int slot = t & 3;
        const u16* as = &As[slot][0];
        const u16* bs = &Bs[slot][0];
        const int ns = (t + 3) & 3;
        const int ko = (t + 3) << 5;
        const bool pf = (t + 3 < T);

        // ---- phase A: A-frags + B n-half 0 ----
        bf16x8 a[8];
        #pragma unroll
        for (int mi = 0; mi < 8; ++mi)
            a[mi] = *(const bf16x8*)(as + aoff[mi]);
        bf16x8 b0 = *(const bf16x8*)(bs + boff[0]);
        bf16x8 b1 = *(const bf16x8*)(bs + boff[1]);
        if (pf) {
            gload_lds16(Ag0 + ko, &As[ns][lb0]);
            gload_lds16(Ag1 + ko, &As[ns][lb1]);
        }
        __builtin_amdgcn_sched_barrier(0);
        __builtin_amdgcn_s_barrier();
        __builtin_amdgcn_sched_barrier(0);
        __builtin_amdgcn_s_setprio(1);
        #pragma unroll
        for (int mi = 0; mi < 8; ++mi) {
            acc[mi][0] = __builtin_amdgcn_mfma_f32_16x16x32_bf16(
                a[mi], b0, acc[mi][0], 0, 0, 0);
            acc[mi][1] = __builtin_amdgcn_mfma_f32_16x16x32_bf16(
                a[mi], b1, acc[mi][1], 0, 0, 0);
        }
        __builtin_amdgcn_s_setprio(0);
        __builtin_amdgcn_sched_barrier(0);
        __builtin_amdgcn_s_barrier();
        __builtin_amdgcn_sched_barrier(0);

        // ---- phase B: B n-half 1 (A-frags reused) ----
        bf16x8 b2 = *(const bf16x8*)(bs + boff[2]);
        bf16x8 b3 = *(const bf16x8*)(bs + boff[3]);
        if (pf) {
            gload_lds16(Bg0 + ko, &Bs[ns][lb0]);
            gload_lds16(Bg1 + ko, &Bs[ns][lb1]);
        }
        __builtin_amdgcn_sched_barrier(0);
        if (t < T - 3) asm volatile("s_waitcnt vmcnt(8)");
        else           asm volatile("s_waitcnt vmcnt(0)");
        __builtin_amdgcn_sched_barrier(0);
        __builtin_amdgcn_s_barrier();
        __builtin_amdgcn_sched_barrier(0);
        __builtin_amdgcn_s_setprio(1);
        #pragma unroll
        for (int mi = 0; mi < 8; ++mi) {
            acc[mi][2] = __builtin_amdgcn_mfma_f32_16x16x32_bf16(
                a[mi], b2, acc[mi][2], 0, 0, 0);
            acc[mi][3] = __builtin_amdgcn_mfma_f32_16x16x32_bf16(
                a[mi], b3, acc[mi][3], 0, 0, 0);
        }
        __builtin_amdgcn_s_setprio(0);
        __builtin_amdgcn_sched_barrier(0);
        __builtin_amdgcn_s_barrier();
        __builtin_amdgcn_sched_barrier(0);   // pin: no next-slot reads hoist
    }

    #pragma unroll
    for (int mi = 0; mi < 8; ++mi) {
        #pragma unroll
        for (int i = 0; i < 4; ++i) {
            int rm = row0 + wm + mi * 16 + qd * 4 + i;
            if (rm >= M) continue;
            #pragma unroll
            for (int ni = 0; ni < 4; ++ni) {
                int cn = col0 + wn + ni * 16 + fr;
                if (cn >= N) continue;
                gemm_epi(acc[mi][ni][i] * scale, rm, cn, epi, Cf, ldc, Cb, ldcb, bias);
            }
        }
    }
}

template<int EPI>
__global__ __launch_bounds__(512, 2)
void bgemm256(const u16* __restrict__ A, int lda,
              const u16* __restrict__ Bm, int ldb,
              int M, int N, int K, float scale,
              float* __restrict__ Cf, int ldc,
              u16* __restrict__ Cb, int ldcb,
              const float* __restrict__ bias,
              int nxt)
{
    // bijective XCD swizzle (grid is a multiple of 8)
    const int g8 = (int)gridDim.x >> 3;
    const int id = (int)blockIdx.x;
    const int w = (id & 7) * g8 + (id >> 3);
    gemm256_body(A, lda, Bm, ldb, M, N, K, scale, Cf, ldc, Cb, ldcb, bias,
                 nxt, EPI, w);
}

// ---------------------------------------------------------------------------
// 8-wave 512-thread SPLIT-K body (round-7) — used ONLY inside kern_mix.
// kern_mix's GEMMs run 135-301 blocks vs ~1024-block device capacity:
// LATENCY-bound on one block's serial K-walk. Split-K-2 halves it:
// 8 waves = 2 K-groups x 4 waves (64x64 quadrants, acc[4][4]); group g walks
// K-tiles [g*Th, (g+1)*Th) in its own LDS double-buffer; then group 1 stashes
// f32 partials in the LDS union (As = wm==0 rows, Bs = wm==64 rows), group 0
// adds and runs the (unchanged) epilogue. All mix K's are multiples of 64.
// T2 swizzle retained (same algebra as gemm_body4). Barriers are block-
// uniform: both groups execute Th iterations + 2 combine barriers.
// ---------------------------------------------------------------------------
__device__ __forceinline__ void gemm_body8(
    const u16* __restrict__ A, int lda,
    const u16* __restrict__ Bm, int ldb,
    int M, int N, int K, float scale,
    float* __restrict__ Cf, int ldc,
    u16* __restrict__ Cb, int ldcb,
    const float* __restrict__ bias,
    int nxt, int swiz, int epi, int id)
{
    __shared__ __align__(16) u16 As[2][2][128 * 32];   // [kgrp][dbuf] 32 KiB
    __shared__ __align__(16) u16 Bs[2][2][128 * 32];   // 32 KiB
    const int tid = threadIdx.x;
    int bx, by;
    if (swiz) { int r8 = id & 7; int q = id >> 3; bx = q % nxt; by = (q / nxt) * 8 + r8; }
    else      { bx = id % nxt; by = id / nxt; }
    const int row0 = by * 128, col0 = bx * 128;
    const int lane = tid & 63, wv = tid >> 6;
    const int kg = wv >> 2;                    // K-half 0/1
    const int ww = wv & 3;                     // wave within group
    const int wm = (ww >> 1) * 64, wn = (ww & 1) * 64;
    const int fr = lane & 15, qd = lane >> 4;

    // staging (per group): 4 waves stage the full 128x32 A/B tiles of this
    // group's K-half; 2 gloads each (rows r0, r0+64). Pre-swizzled source
    // slot (same XOR algebra as gemm_body4: chunk c = ww*64+lane (+256) ->
    // row = c>>2, (row>>1)&3 = (lane>>3)&3 since ww*8, 32 are both == 0 mod 4).
    const int r0   = ww * 16 + (lane >> 2);
    const int s_sw = ((lane & 3) ^ ((lane >> 3) & 3)) * 8;
    const u16* Ag0 = A  + (size_t)(row0 + r0) * lda + s_sw;
    const u16* Ag1 = A  + (size_t)(row0 + r0 + 64) * lda + s_sw;
    const u16* Bg0 = Bm + (size_t)(col0 + r0) * ldb + s_sw;
    const u16* Bg1 = Bm + (size_t)(col0 + r0 + 64) * ldb + s_sw;
    const int lb0 = ww * 512, lb1 = 2048 + ww * 512;   // u16, wave-uniform
    const int qsw = (qd ^ ((fr >> 1) & 3)) * 8;        // swizzled read slot

    f32x4 acc[4][4] = {};
    const int Th = K >> 6;                     // tiles per half (K mult of 64)
    const int kb = kg * Th;                    // first tile of this half

    gload_lds16(Ag0 + (kb << 5), &As[kg][0][lb0]);
    gload_lds16(Ag1 + (kb << 5), &As[kg][0][lb1]);
    gload_lds16(Bg0 + (kb << 5), &Bs[kg][0][lb0]);
    gload_lds16(Bg1 + (kb << 5), &Bs[kg][0][lb1]);

    for (int i = 0; i < Th; ++i) {
        __syncthreads();
        const int cur = i & 1;
        if (i + 1 < Th) {
            const int ko = (kb + i + 1) << 5;
            gload_lds16(Ag0 + ko, &As[kg][cur ^ 1][lb0]);
            gload_lds16(Ag1 + ko, &As[kg][cur ^ 1][lb1]);
            gload_lds16(Bg0 + ko, &Bs[kg][cur ^ 1][lb0]);
            gload_lds16(Bg1 + ko, &Bs[kg][cur ^ 1][lb1]);
        }
        bf16x8 af[4], bg[4];
        #pragma unroll
        for (int j = 0; j < 4; ++j) {
            af[j] = *(const bf16x8*)&As[kg][cur][(wm + j * 16 + fr) * 32 + qsw];
            bg[j] = *(const bf16x8*)&Bs[kg][cur][(wn + j * 16 + fr) * 32 + qsw];
        }
        #pragma unroll
        for (int mi = 0; mi < 4; ++mi)
            #pragma unroll
            for (int ni = 0; ni < 4; ++ni)
                acc[mi][ni] = __builtin_amdgcn_mfma_f32_16x16x32_bf16(
                    af[mi], bg[ni], acc[mi][ni], 0, 0, 0);
    }

    // cross-group K-reduction via the LDS union (all staging reads complete
    // before the barrier; 64x128 f32 per half fits exactly in As resp. Bs).
    __syncthreads();
    float* Cs = (wm == 0) ? (float*)As : (float*)Bs;
    if (kg == 1) {
        #pragma unroll
        for (int mi = 0; mi < 4; ++mi)
            #pragma unroll
            for (int i = 0; i < 4; ++i)
                #pragma unroll
                for (int ni = 0; ni < 4; ++ni)
                    Cs[(mi * 16 + qd * 4 + i) * 128 + wn + ni * 16 + fr] =
                        acc[mi][ni][i];
    }
    __syncthreads();
    if (kg == 0) {
        #pragma unroll
        for (int mi = 0; mi < 4; ++mi) {
            #pragma unroll
            for (int i = 0; i < 4; ++i) {
                int rm = row0 + wm + mi * 16 + qd * 4 + i;
                #pragma unroll
                for (int ni = 0; ni < 4; ++ni) {
                    int cn = col0 + wn + ni * 16 + fr;
                    float v = acc[mi][ni][i] +
                        Cs[(mi * 16 + qd * 4 + i) * 128 + wn + ni * 16 + fr];
                    if (rm < M && cn < N)
                        gemm_epi(v * scale, rm, cn, epi, Cf, ldc, Cb, ldcb, bias);
                }
            }
        }
    }
}

// ---------------------------------------------------------------------------
// Mixed launch: grouped small GEMMs + cast-transpose tiles + PARALLEL
// adjacency in one 512-thread dispatch.
// ---------------------------------------------------------------------------
struct GDesc {
    const u16* A; const u16* B; float* Cf; u16* Cb; const float* bias;
    int lda, ldb, ldc, ldcb, M, N, K, epi, nxt, swiz, blk0;
    float scale;
};
struct TDesc { const float* src; u16* dst; int srs, drs, rows, cols, padrows, rt, nblk; };
struct MPack { GDesc g[3]; TDesc t[2]; const int* ei; float* Adj; int ng, gtot, nt; };

// Coalesced LDS-tiled cast-transpose tile (512 threads: 32x16, 2 rows each).
__device__ __forceinline__ void castT_body(TDesc T, int id)
{
    __shared__ float t[32][33];
    const int bx = id % T.rt, by = id / T.rt;
    const int r0 = bx * 32, c0 = by * 32;
    const int tx = threadIdx.x & 31, ty = threadIdx.x >> 5;   // ty 0..15
    #pragma unroll
    for (int k = 0; k < 2; ++k) {
        int r = r0 + ty + k * 16, c = c0 + tx;
        t[ty + k * 16][tx] = (r < T.rows && c < T.cols) ? T.src[(size_t)r * T.srs + c] : 0.f;
    }
    __syncthreads();
    #pragma unroll
    for (int k = 0; k < 2; ++k) {
        int c = c0 + ty + k * 16, r = r0 + tx;
        if (c < T.cols && r < T.padrows)
            T.dst[(size_t)c * T.drs + r] = f2bf(t[tx][ty + k * 16]);
    }
}

// PARALLEL dense 14x14 GCN adjacency + colw.
__device__ __forceinline__ void adj_body(const int* __restrict__ ei, float* __restrict__ Adj)
{
    __shared__ float degS[NN_], dinvS[NN_], adjS[NN_ * NN_];
    const int tid = threadIdx.x;
    if (tid < NN_) degS[tid] = 1.f;
    if (tid < NN_ * NN_) adjS[tid] = 0.f;
    __syncthreads();
    int s = 0, d = 0;
    if (tid < EE_) { s = ei[tid]; d = ei[EE_ + tid]; atomicAdd(&degS[d], 1.f); }
    __syncthreads();
    if (tid < NN_) dinvS[tid] = rsqrtf(degS[tid]);
    __syncthreads();
    if (tid < EE_) atomicAdd(&adjS[d * NN_ + s], dinvS[s] * dinvS[d]);
    if (tid < NN_) atomicAdd(&adjS[tid * NN_ + tid], dinvS[tid] * dinvS[tid]);
    __syncthreads();
    if (tid < NN_ * NN_) Adj[tid] = adjS[tid];
    if (tid < 16) {
        float sum = 0.f;
        if (tid < NN_)
            for (int j = 0; j < NN_; ++j) sum += adjS[j * NN_ + tid];
        Adj[NN_ * NN_ + tid] = sum / (float)NN_;
    }
}

__global__ __launch_bounds__(512, 4)
void kern_mix(MPack p)
{
    int id = blockIdx.x;
    if (id < p.gtot) {
        int si = 0;
        for (int s = 1; s < p.ng; ++s) if (id >= p.g[s].blk0) si = s;
        GDesc D = p.g[si];
        gemm_body8(D.A, D.lda, D.B, D.ldb, D.M, D.N, D.K, D.scale,
                   D.Cf, D.ldc, D.Cb, D.ldcb, D.bias, D.nxt, D.swiz, D.epi,
                   id - D.blk0);
        return;
    }
    id -= p.gtot;
    for (int s = 0; s < p.nt; ++s) {
        if (id < p.t[s].nblk) { castT_body(p.t[s], id); return; }
        id -= p.t[s].nblk;
    }
    if (id == 0 && p.ei) adj_body(p.ei, p.Adj);
}

// Multi-segment fp32->bf16 cast (+ zero-fill segments with scols=0).
struct CDesc { const float* src; u16* dst; int srs, drs, dcols, scols; };
struct CPack { CDesc d[9]; unsigned cum[10]; int n; };

__global__ void kern_mcast(CPack p)
{
    unsigned idx = blockIdx.x * 256 + threadIdx.x;
    int si = -1;
    for (int s = 0; s < p.n; ++s)
        if (idx >= p.cum[s] && idx < p.cum[s + 1]) { si = s; break; }
    if (si < 0) return;
    CDesc D = p.d[si];
    unsigned k = idx - p.cum[si];
    int r = k / D.dcols, c = k - r * D.dcols;
    D.dst[(size_t)r * D.drs + c] =
        (c < D.scols) ? f2bf(D.src[(size_t)r * D.srs + c]) : (u16)0;
}

// Fused [ew rowmax+exp] + exp(S0) + G + Z.
__global__ __launch_bounds__(256) void kern_eG(const float* __restrict__ S,
    u16* __restrict__ Gb, float* __restrict__ Z)
{
    __shared__ float red[256];
    __shared__ u16 ews[NN_ * 1024];   // 28.7 KB
    const int l = blockIdx.x, tid = threadIdx.x;
    const int lane = tid & 63, wv = tid >> 6;

    const float* wraw = S + 1024 * 1024;
    for (int z = wv; z < NN_; z += 4) {
        const float* r = wraw + z * 1024;
        float vv[16], mx = -1e30f;
        #pragma unroll
        for (int j = 0; j < 16; ++j) { vv[j] = r[lane + 64 * j]; mx = fmaxf(mx, vv[j]); }
        #pragma unroll
        for (int off = 32; off > 0; off >>= 1) mx = fmaxf(mx, __shfl_down(mx, off));
        mx = __shfl(mx, 0);
        #pragma unroll
        for (int j = 0; j < 16; ++j)
            ews[z * 1024 + lane + 64 * j] = f2bf(expf(vv[j] - mx));
    }
    const float* row = S + (size_t)l * 1024;
    float m = -1e30f;
    #pragma unroll
    for (int k = 0; k < 4; ++k) m = fmaxf(m, row[tid + 256 * k]);
    red[tid] = m; __syncthreads();          // also publishes ews
    for (int s = 128; s > 0; s >>= 1) {
        if (tid < s) red[tid] = fmaxf(red[tid], red[tid + s]);
        __syncthreads();
    }
    m = red[0];
    float ev[16];
    #pragma unroll
    for (int j = 0; j < 16; ++j) ev[j] = expf(row[lane + 64 * j] - m);
    u16* gr = Gb + (size_t)l * NN_ * 1024;
    for (int z = wv; z < NN_; z += 4) {
        const u16* er = &ews[z * 1024];
        float s = 0.f;
        #pragma unroll
        for (int j = 0; j < 16; ++j) {
            float pv = ev[j] * bf2f(er[lane + 64 * j]);
            gr[(size_t)z * 1024 + lane + 64 * j] = f2bf(pv);
            s += pv;
        }
        #pragma unroll
        for (int off = 32; off > 0; off >>= 1) s += __shfl_down(s, off);
        if (lane == 0) Z[l * NN_ + z] = s;
    }
}

// x1 = LN1(node + Pb + co); Pb is bf16 attn-out already scaled by 1/Z.
// ROUND-7: vectorized (G13) — float4/short4 loads (alignments: Pb rows 8B,
// co/img/word 16B), short8 stores (X1b rows 16B); values kept in registers
// across the two reduction passes. Was all-scalar (2-2.5x memory penalty).
__global__ __launch_bounds__(256) void kern_ln1(
    const float* __restrict__ img, const float* __restrict__ word,
    const u16* __restrict__ Pb,
    const float* __restrict__ co, const float* __restrict__ g,
    const float* __restrict__ bta, u16* __restrict__ Xb)
{
    __shared__ float buf[816];
    __shared__ float red[256];
    __shared__ float stats[2];
    int row = blockIdx.x;
    int b = row / NN_, n = row - b * NN_;
    const u16* pr = Pb + (size_t)row * DD_;
    const float* cr = co + n * DD_;
    const int t = threadIdx.x;
    float v0 = 0.f, v1 = 0.f, v2 = 0.f, v3 = 0.f;
    float s = 0.f;
    if (t < 203) {                         // 203*4 = 812 = DD_
        const int d = t * 4;
        float4 iv = (d < IMG_) ? *(const float4*)&img[(size_t)b * IMG_ + d]
                               : *(const float4*)&word[n * TXT_ + (d - IMG_)];
        u16x4 pv = *(const u16x4*)&pr[d];
        float4 cv = *(const float4*)&cr[d];
        v0 = iv.x + bf2f(pv[0]) + cv.x;
        v1 = iv.y + bf2f(pv[1]) + cv.y;
        v2 = iv.z + bf2f(pv[2]) + cv.z;
        v3 = iv.w + bf2f(pv[3]) + cv.w;
        buf[d] = v0; buf[d + 1] = v1; buf[d + 2] = v2; buf[d + 3] = v3;
        s = v0 + v1 + v2 + v3;
    }
    red[t] = s; __syncthreads();
    for (int k = 128; k > 0; k >>= 1) {
        if (t < k) red[t] += red[t + k];
        __syncthreads();
    }
    if (t == 0) stats[0] = red[0] / DD_;
    __syncthreads();
    float mu = stats[0];
    float s2 = 0.f;
    if (t < 203) {
        float a0 = v0 - mu, a1 = v1 - mu, a2 = v2 - mu, a3 = v3 - mu;
        s2 = a0 * a0 + a1 * a1 + a2 * a2 + a3 * a3;
    }
    red[t] = s2; __syncthreads();
    for (int k = 128; k > 0; k >>= 1) {
        if (t < k) red[t] += red[t + k];
        __syncthreads();
    }
    if (t == 0) stats[1] = rsqrtf(red[0] / DD_ + 1e-5f);
    __syncthreads();
    float rstd = stats[1];
    u16* xb = Xb + (size_t)row * KP_;
    if (t < 104) {                          // 104*8 = 832 = KP_ (incl pad)
        const int d = t * 8;
        u16x8 o;
        #pragma unroll
        for (int k = 0; k < 8; ++k) {
            int dd = d + k;
            o[k] = (dd < DD_)
                 ? f2bf((buf[dd] - mu) * rstd * g[dd] + bta[dd]) : (u16)0;
        }
        *(u16x8*)&xb[d] = o;
    }
}

// ---------------------------------------------------------------------------
// Fused LN2 + GCN1 + GCN2 + mean-pool + linear. One block per image b.
// ---------------------------------------------------------------------------
#define X2S_ 840
#define G1S_ 136
__global__ __launch_bounds__(256, 4)
void kern_gcn(const u16* __restrict__ Yb,
              const float* __restrict__ g2v, const float* __restrict__ bt2,
              const u16* __restrict__ Wg1T, const float* __restrict__ bg1,
              const u16* __restrict__ Wg2T, const float* __restrict__ bg2,
              const float* __restrict__ Wl,  const float* __restrict__ bl,
              const float* __restrict__ AdjW, float* __restrict__ out)
{
    __shared__ __align__(16) u16 x2s[16 * X2S_];      // 26.9 KB; g1s overlays
    __shared__ __align__(16) float h1s[16 * 132];     // 8.4 KB
    __shared__ float adj_s[NN_ * NN_];
    __shared__ float colw_s[16];
    __shared__ float pool_s[HID_];
    u16* g1s = x2s;                                   // overlay (16*G1S_ u16)
    const int b = blockIdx.x, tid = threadIdx.x;
    const int lane = tid & 63, wv = tid >> 6;
    const int fr = lane & 15, qd = lane >> 4;

    if (tid < NN_ * NN_) adj_s[tid] = AdjW[tid];
    if (tid >= NN_ * NN_ && tid < NN_ * NN_ + 16) colw_s[tid - NN_ * NN_] = AdjW[tid];
    for (int k = tid; k < 2 * X2S_; k += 256) x2s[14 * X2S_ + k] = 0;
    for (int k = tid; k < 14 * (X2S_ - DD_); k += 256) {
        int j = k / (X2S_ - DD_), c = k - j * (X2S_ - DD_);
        x2s[j * X2S_ + DD_ + c] = 0;
    }

    // --- LN2 per node row ---
    for (int j = wv; j < NN_; j += 4) {
        const u16* yr = Yb + (size_t)(b * NN_ + j) * KP_;
        float vv[13], s = 0.f;
        #pragma unroll
        for (int k = 0; k < 13; ++k) {
            int d = lane + 64 * k;
            float v = (d < DD_) ? bf2f(yr[d]) : 0.f;
            vv[k] = v; s += v;
        }
        #pragma unroll
        for (int off = 32; off > 0; off >>= 1) s += __shfl_down(s, off);
        s = __shfl(s, 0);
        float mu = s / (float)DD_, s2 = 0.f;
        #pragma unroll
        for (int k = 0; k < 13; ++k) {
            int d = lane + 64 * k;
            float t = (d < DD_) ? vv[k] - mu : 0.f;
            s2 += t * t;
        }
        #pragma unroll
        for (int off = 32; off > 0; off >>= 1) s2 += __shfl_down(s2, off);
        s2 = __shfl(s2, 0);
        float rstd = rsqrtf(s2 / (float)DD_ + 1e-5f);
        #pragma unroll
        for (int k = 0; k < 13; ++k) {
            int d = lane + 64 * k;
            if (d < DD_)
                x2s[j * X2S_ + d] = f2bf((vv[k] - mu) * rstd * g2v[d] + bt2[d]);
        }
    }
    __syncthreads();

    // --- GCN1 (MFMA, M=16, K=KP_) ---
    {
        f32x4 acc[2] = {{}, {}};
        const u16* wp0 = Wg1T + (size_t)(wv * 32 + fr) * KP_ + qd * 8;
        const u16* wp1 = wp0 + (size_t)16 * KP_;
        bf16x8 bc0 = *(const bf16x8*)wp0;
        bf16x8 bc1 = *(const bf16x8*)wp1;
        for (int k0 = 0; k0 < KP_; k0 += 32) {
            bf16x8 bn0 = bc0, bn1 = bc1;
            if (k0 + 32 < KP_) {
                bn0 = *(const bf16x8*)(wp0 + k0 + 32);
                bn1 = *(const bf16x8*)(wp1 + k0 + 32);
            }
            bf16x8 af = *(const bf16x8*)&x2s[fr * X2S_ + k0 + qd * 8];
            acc[0] = __builtin_amdgcn_mfma_f32_16x16x32_bf16(af, bc0, acc[0], 0, 0, 0);
            acc[1] = __builtin_amdgcn_mfma_f32_16x16x32_bf16(af, bc1, acc[1], 0, 0, 0);
            bc0 = bn0; bc1 = bn1;
        }
        #pragma unroll
        for (int t = 0; t < 2; ++t)
            #pragma unroll
            for (int i = 0; i < 4; ++i)
                h1s[(qd * 4 + i) * 132 + wv * 32 + t * 16 + fr] = acc[t][i];
    }
    __syncthreads();   // x2s dead; g1s overlay now writable

    // --- G1 = relu(Adj @ H1 + bg1) -> bf16; zero pad rows 14,15 ---
    {
        const int f = tid & 127, jj = (tid >> 7) * 7;
        #pragma unroll
        for (int j = 0; j < 7; ++j) {
            float s = bg1[f];
            #pragma unroll
            for (int i = 0; i < NN_; ++i)
                s = fmaf(adj_s[(jj + j) * NN_ + i], h1s[i * 132 + f], s);
            g1s[(jj + j) * G1S_ + f] = f2bf(s > 0.f ? s : 0.f);
        }
        for (int k = tid; k < 2 * G1S_; k += 256) g1s[14 * G1S_ + k] = 0;
    }
    __syncthreads();

    // --- GCN2 (MFMA, K=128) + pool = relu(colw·H2 + bg2) ---
    {
        f32x4 acc[2] = {{}, {}};
        const u16* wp0 = Wg2T + (size_t)(wv * 32 + fr) * HID_ + qd * 8;
        const u16* wp1 = wp0 + (size_t)16 * HID_;
        bf16x8 bc0 = *(const bf16x8*)wp0;
        bf16x8 bc1 = *(const bf16x8*)wp1;
        for (int k0 = 0; k0 < HID_; k0 += 32) {
            bf16x8 bn0 = bc0, bn1 = bc1;
            if (k0 + 32 < HID_) {
                bn0 = *(const bf16x8*)(wp0 + k0 + 32);
                bn1 = *(const bf16x8*)(wp1 + k0 + 32);
            }
            bf16x8 af = *(const bf16x8*)&g1s[fr * G1S_ + k0 + qd * 8];
            acc[0] = __builtin_amdgcn_mfma_f32_16x16x32_bf16(af, bc0, acc[0], 0, 0, 0);
            acc[1] = __builtin_amdgcn_mfma_f32_16x16x32_bf16(af, bc1, acc[1], 0, 0, 0);
            bc0 = bn0; bc1 = bn1;
        }
        #pragma unroll
        for (int t = 0; t < 2; ++t) {
            float s = 0.f;
            #pragma unroll
            for (int i = 0; i < 4; ++i) s += colw_s[qd * 4 + i] * acc[t][i];
            s += __shfl_xor(s, 16);
            s += __shfl_xor(s, 32);
            if (qd == 0) {
                int f = wv * 32 + t * 16 + fr;
                float p = s + bg2[f];
                pool_s[f] = p > 0.f ? p : 0.f;
            }
        }
    }
    __syncthreads();

    // --- out = pool @ Wl + bl ---
    if (tid < CC_) {
        float s = bl[tid];
        #pragma unroll 8
        for (int f = 0; f < HID_; ++f)
            s = fmaf(pool_s[f], Wl[(size_t)f * CC_ + tid], s);
        out[(size_t)b * CC_ + tid] = s;
    }
}

extern "C" void kernel_launch(void* const* d_in, const int* in_sizes, int n_in,
                              void* d_out, int out_size, void* d_ws, size_t ws_size,
                              hipStream_t stream)
{
    const float* img  = (const float*)d_in[0];
    const float* word = (const float*)d_in[1];
    const int*   ei   = (const int*)d_in[2];
    const float* Wi   = (const float*)d_in[3];
    const float* bi   = (const float*)d_in[4];
    const float* Wo   = (const float*)d_in[5];
    const float* bo   = (const float*)d_in[6];
    const float* g1   = (const float*)d_in[7];
    const float* bt1  = (const float*)d_in[8];
    const float* g2   = (const float*)d_in[9];
    const float* bt2  = (const float*)d_in[10];
    const float* W1   = (const float*)d_in[11];
    const float* bf1  = (const float*)d_in[12];
    const float* W2   = (const float*)d_in[13];
    const float* bf2  = (const float*)d_in[14];
    const float* Wg1  = (const float*)d_in[15];
    const float* bg1  = (const float*)d_in[16];
    const float* Wg2  = (const float*)d_in[17];
    const float* bg2  = (const float*)d_in[18];
    const float* Wl   = (const float*)d_in[19];
    const float* bl   = (const float*)d_in[20];
    float* out = (float*)d_out;

    char* ws = (char*)d_ws;
    u16*   imgb = (u16*)  (ws + OFF_IMGB);
    u16*   Wib  = (u16*)  (ws + OFF_WIB);
    u16*   wordb= (u16*)  (ws + OFF_WORDB);
    u16*   WiTX = (u16*)  (ws + OFF_WITX);
    u16*   Gb   = (u16*)  (ws + OFF_GB);
    float* Ebuf = (float*)(ws + OFF_EBUF);
    u16*   AvoT = (u16*)  (ws + OFF_AVOT);
    u16*   Wob  = (u16*)  (ws + OFF_WOB);
    u16*   Hb   = (u16*)  (ws + OFF_HB);
    u16*   Pb   = (u16*)  (ws + OFF_PB);
    u16*   X1b  = (u16*)  (ws + OFF_X1B);
    u16*   Yb   = (u16*)  (ws + OFF_YB);
    u16*   W1T  = (u16*)  (ws + OFF_W1T);
    u16*   W2T  = (u16*)  (ws + OFF_W2T);
    u16*   Aqb  = (u16*)  (ws + OFF_AQB);
    u16*   Akb  = Aqb + AROWS_ * KP_;
    u16*   Avb  = Aqb + 2 * AROWS_ * KP_;
    u16*   Tvb  = (u16*)  (ws + OFF_TVB);
    float* co   = (float*)(ws + OFF_CO);
    float* Zb   = (float*)(ws + OFF_Z);
    float* Adj  = (float*)(ws + OFF_ADJ);
    u16*   Wg1T = (u16*)  (ws + OFF_WG1T);
    u16*   Wg2T = (u16*)  (ws + OFF_WG2T);

    const float scl = 1.0f / sqrtf((float)DD_);

    // --- launch 1: multi-cast (input casts + all K-pad zeroing) ---
    {
        CPack p; p.n = 9;
        unsigned c = 0;
        auto seg = [&](int i, const float* s, int srs, u16* d, int drs,
                       int rows, int dcols, int scols) {
            p.d[i] = { s, d, srs, drs, dcols, scols };
            p.cum[i] = c; c += (unsigned)rows * dcols;
        };
        seg(0, img,        IMG_, imgb,  IMG_, B_,   IMG_, IMG_);
        seg(1, Wi,         DD_,  Wib,   IMG_, D3_,  IMG_, IMG_);
        seg(2, word,       TXT_, wordb, TXP_, NN_,  TXP_, TXT_);
        seg(3, Wi + IMG_,  DD_,  WiTX,  TXP_, D3_,  TXP_, TXT_);
        seg(4, Wo,         DD_,  Wob,   KP_,  DD_,  KP_,  DD_);
        seg(5, nullptr, 0, Aqb + DD_,                    KP_, 1038, 20, 0); // Aq + Tq rows
        seg(6, nullptr, 0, Aqb + AROWS_ * KP_ + DD_,     KP_, 1024, 20, 0);
        seg(7, nullptr, 0, Aqb + 2 * AROWS_ * KP_ + DD_, KP_, 1024, 20, 0);
        seg(8, nullptr, 0, Tvb + DD_,                    KP_, NN_,  20, 0); // Tvb pads
        p.cum[9] = c;
        kern_mcast<<<(c + 255) / 256, 256, 0, stream>>>(p);
    }

    // --- launch 2 (mix1): T epi8 + A-proj || Wg1T/Wg2T transposes || adj ---
    {
        MPack p{};
        p.ng = 2; p.gtot = 180;
        p.g[0] = { wordb, WiTX, (float*)Tvb, Aqb, bi,
                   TXP_, TXP_, 0, 0, NN_, D3_, TXP_, 8, 20, 0, 0, 1.f };
        p.g[1] = { imgb, Wib, nullptr, Aqb, nullptr,
                   IMG_, IMG_, 0, 0, B_, D3_, IMG_, 4, 20, 1, 20, 1.f };
        p.nt = 2;
        p.t[0] = { Wg1, Wg1T, HID_, KP_,  DD_,  HID_, KP_,  26, 26 * 4 };
        p.t[1] = { Wg2, Wg2T, HID_, HID_, HID_, HID_, HID_, 4,  4 * 4 };
        p.ei = ei; p.Adj = Adj;
        kern_mix<<<180 + 104 + 16 + 1, 512, 0, stream>>>(p);
    }

    // --- launch 3 (mix2): S0+w || AvoT || co  ||  W1T/W2T transposes ---
    {
        MPack p{};
        p.ng = 3; p.gtot = 135;
        p.g[0] = { Aqb, Akb, Ebuf, nullptr, nullptr,
                   KP_, KP_, 1024, 0, 1024 + NN_, 1024, KP_, 0, 8, 0, 0, scl };
        p.g[1] = { Wob, Avb, nullptr, AvoT, nullptr,
                   KP_, KP_, 0, 1024, DD_, B_, KP_, 3, 8, 0, 72, 1.f };
        p.g[2] = { Tvb, Wob, co, nullptr, bo,
                   KP_, KP_, DD_, 0, NN_, DD_, KP_, 6, 7, 0, 128, 1.f };
        p.nt = 2;
        p.t[0] = { W1, W1T, FF_, KP_, DD_, FF_, KP_, 26, 26 * 64 };
        p.t[1] = { W2, W2T, DD_, FF_, FF_, DD_, FF_, 64, 64 * 26 };
        p.ei = nullptr; p.Adj = nullptr;
        kern_mix<<<135 + 1664 + 1664, 512, 0, stream>>>(p);
    }

    // --- launch 4: fused ew-exp + exp + G + Z ---
    kern_eG<<<1024, 256, 0, stream>>>(Ebuf, Gb, Zb);

    // --- launch 5: Pb = (G @ Avo)/Z as bf16 (128^2 4-wave body, swizzled) ---
    bgemm<5><<<7 * 112, 256, 0, stream>>>(Gb, 1024, AvoT, 1024,
        BNR_, DD_, 1024, 1.f, nullptr, 0, Pb, DD_, Zb, 7, 1);

    // --- launch 6: LN1 (vectorized) ---
    kern_ln1<<<BNR_, 256, 0, stream>>>(img, word, Pb, co, g1, bt1, X1b);

    // --- launch 7: FFN1 (128^2 4-wave body, swizzled — 1792 blocks ~4/CU) ---
    bgemm<1><<<16 * 112, 256, 0, stream>>>(X1b, KP_, W1T, KP_,
        BNR_, FF_, KP_, 1.f, nullptr, 0, Hb, FF_, bf1, 16, 1);

    // --- launch 8: FFN2 (256^2 phased body — 224 blocks, 1 clean round) ---
    bgemm256<7><<<56 * 4, 512, 0, stream>>>(Hb, FF_, W2T, FF_,
        BNR_, DD_, FF_, 1.f, (float*)X1b, KP_, Yb, KP_, bf2, 4);

    // --- launch 9: fused LN2 + GCN1 + GCN2 + pool + linear ---
    kern_gcn<<<B_, 256, 0, stream>>>(Yb, g2, bt2, Wg1T, bg1, Wg2T, bg2,
                                     Wl, bl, Adj, out);
}

// Round 8
// 473.229 us; speedup vs baseline: 1.0186x; 1.0186x over previous
//
#include <hip/hip_runtime.h>
#include <math.h>

// Problem constants
#define B_    1024
#define IMG_  512
#define TXT_  300
#define NN_   14
#define FF_   2048
#define HID_  128
#define CC_   14
#define EE_   182
#define DD_   812
#define D3_   2436
#define BNR_  14336          // B_*NN_
#define KP_   832            // 812 padded to /32 (16B-aligned rows)
#define TXP_  320            // 300 padded to /32
#define AROWS_ 1152          // Aq/Ak/Av rows: 1024 data + 14 Tq + pad to tile mult

typedef __bf16 bf16x8 __attribute__((ext_vector_type(8)));
typedef float  f32x4  __attribute__((ext_vector_type(4)));
typedef unsigned short u16;
typedef unsigned short u16x4 __attribute__((ext_vector_type(4)));
typedef unsigned short u16x8 __attribute__((ext_vector_type(8)));

__device__ __forceinline__ u16 f2bf(float f) {
    union { float f; unsigned u; } v; v.f = f;
    unsigned r = v.u + 0x7FFFu + ((v.u >> 16) & 1u);   // RNE
    return (u16)(r >> 16);
}
__device__ __forceinline__ float bf2f(u16 h) {
    union { unsigned u; float f; } v; v.u = ((unsigned)h) << 16; return v.f;
}

// async global->LDS, 16B per lane. HW contract (m104/m108): LDS dst must be
// a WAVE-UNIFORM base; lane i's data lands at base + i*16. Global src is
// per-lane.
__device__ __forceinline__ void gload_lds16(const u16* g, u16* l) {
    __builtin_amdgcn_global_load_lds(
        (const __attribute__((address_space(1))) void*)g,
        (__attribute__((address_space(3))) void*)l, 16, 0, 0);
}

// ---------------------------------------------------------------------------
// Workspace layout (bytes), time-multiplexed overlays.
// ---------------------------------------------------------------------------
#define OFF_IMGB  0ULL              // bf16 [1024][512]
#define OFF_WIB   1048576ULL        // bf16 [2436][512]
#define OFF_WORDB 3543040ULL        // bf16 [128][320]
#define OFF_WITX  3624960ULL        // bf16 [2560][320]
#define OFF_GB    0ULL              // bf16 [14336][1024] (eG..P)
#define OFF_EBUF  29360128ULL       // f32  [1038][1024]  (S0..eG)
#define OFF_AVOT  33611776ULL       // bf16 [896][1024]   (mix2..P)
#define OFF_WOB   35446784ULL       // bf16 [896][832]    (mcast..mix2)
#define OFF_HB    0ULL              // bf16 [14336][2048] (FFN1..FFN2)
#define OFF_PB    58720256ULL       // bf16 [14336][812]  (P..ln1)
#define OFF_X1B   82001920ULL       // bf16 [14336][832]  (ln1..FFN2)
#define OFF_YB    105857024ULL      // bf16 [14336][832]  (FFN2..gcn)
#define OFF_W1T   129712128ULL      // bf16 [2048][832]   (mix2..FFN1)
#define OFF_W2T   133120000ULL      // bf16 [896][2048]   (mix2..FFN2)
#define OFF_AQB   152420352ULL      // bf16 3x[1152][832] (Aq|Ak|Av)
#define OFF_TVB   158307552ULL      // bf16 [128][832]
#define OFF_CO    158520544ULL      // f32  [14][812]
#define OFF_Z     158566016ULL      // f32  [14336]
#define OFF_ADJ   158623360ULL      // f32  [196 adj + 16 colw]
#define OFF_WG1T  158624384ULL      // bf16 [128][832]
#define OFF_WG2T  158837376ULL      // bf16 [128][128]

// ---------------------------------------------------------------------------
// epi 0: Cf=v. 1: Cb=bf16(relu(v+bias[cn])). 2: Cf=v+bias[cn]+bf2f(Cb).
// 3: Cb=bf16(v). 4: split-3 into [Aq|Ak|Av]. 5: Cb=bf16(v/bias[rm]).
// 6: Cf=v+bias[cn]. 7: Cb=bf16(v+bias[cn]+bf2f(((u16*)Cf)[rm*ldc+cn])).
// 8: T-split: cn<812 -> Cb[(1024+rm)*KP_+cn]; cn>=1624 -> ((u16*)Cf)[rm*KP_+cn-1624].
// ---------------------------------------------------------------------------
__device__ __forceinline__ void gemm_epi(
    float v, int rm, int cn, int epi,
    float* __restrict__ Cf, int ldc, u16* __restrict__ Cb, int ldcb,
    const float* __restrict__ bias)
{
    if (epi == 0) Cf[(size_t)rm * ldc + cn] = v;
    else if (epi == 1) { v += bias[cn]; v = v > 0.f ? v : 0.f;
                    Cb[(size_t)rm * ldcb + cn] = f2bf(v); }
    else if (epi == 2) Cf[(size_t)rm * ldc + cn] =
                    v + bias[cn] + bf2f(Cb[(size_t)rm * ldcb + cn]);
    else if (epi == 3) Cb[(size_t)rm * ldcb + cn] = f2bf(v);
    else if (epi == 4) { int bs = cn / DD_, cc = cn - bs * DD_;
                    Cb[(size_t)bs * (AROWS_ * KP_) + (size_t)rm * KP_ + cc] = f2bf(v); }
    else if (epi == 5) { float invz = 1.0f / bias[rm];
                    Cb[(size_t)rm * ldcb + cn] = f2bf(v * invz); }
    else if (epi == 6) Cf[(size_t)rm * ldc + cn] = v + bias[cn];
    else if (epi == 7) { const u16* rx = (const u16*)Cf;
                    Cb[(size_t)rm * ldcb + cn] =
                        f2bf(v + bias[cn] + bf2f(rx[(size_t)rm * ldc + cn])); }
    else if (epi == 8) {
        float t = v + bias[cn];
        if (cn < DD_) Cb[(size_t)(1024 + rm) * KP_ + cn] = f2bf(t);
        else if (cn >= 2 * DD_)
            ((u16*)Cf)[(size_t)rm * KP_ + (cn - 2 * DD_)] = f2bf(t);
    }
}

// ---------------------------------------------------------------------------
// 4-wave GEMM body: 128x128 tile, BK=32, 256 threads, 2x2 waves of 64x64,
// double-buffered global_load_lds, 32 KiB LDS -> 4 blocks/CU (register-capped
// at 120 regs/wave incl AGPR). T2 both-sides XOR swizzle (round-6; conflicts
// 6.4M -> 0, perf-neutral at this TLP — kept for free). Used for FFN1 and
// launch-5 where block count >> CU capacity (throughput regime).
// ---------------------------------------------------------------------------
__device__ __forceinline__ void gemm_body4(
    const u16* __restrict__ A, int lda,
    const u16* __restrict__ Bm, int ldb,
    int M, int N, int K, float scale,
    float* __restrict__ Cf, int ldc,
    u16* __restrict__ Cb, int ldcb,
    const float* __restrict__ bias,
    int nxt, int swiz, int epi, int id)
{
    __shared__ __align__(16) u16 As[2][128 * 32];
    __shared__ __align__(16) u16 Bs[2][128 * 32];
    const int tid = threadIdx.x;
    int bx, by;
    if (swiz) { int r8 = id & 7; int q = id >> 3; bx = q % nxt; by = (q / nxt) * 8 + r8; }
    else      { bx = id % nxt; by = id / nxt; }
    const int row0 = by * 128, col0 = bx * 128;
    const int lane = tid & 63, wv = tid >> 6;
    const int wm = (wv >> 1) * 64, wn = (wv & 1) * 64;
    const int fr = lane & 15, qd = lane >> 4;

    const int s_r0  = (wv * 64 + lane) >> 2;
    const int s_sw  = ((lane & 3) ^ ((lane >> 3) & 3)) * 8;   // swizzled src slot
    const int s_b0  = (wv * 64) * 8;
    const u16* Arow0 = A  + (size_t)(row0 + s_r0) * lda + s_sw;
    const u16* Arow1 = A  + (size_t)(row0 + s_r0 + 64) * lda + s_sw;
    const u16* Brow0 = Bm + (size_t)(col0 + s_r0) * ldb + s_sw;
    const u16* Brow1 = Bm + (size_t)(col0 + s_r0 + 64) * ldb + s_sw;
    const int qsw = (qd ^ ((fr >> 1) & 3)) * 8;               // swizzled read slot

    f32x4 acc[4][4] = {};

    const int T = K >> 5;
    gload_lds16(Arow0, &As[0][s_b0]);
    gload_lds16(Arow1, &As[0][s_b0 + 2048]);
    gload_lds16(Brow0, &Bs[0][s_b0]);
    gload_lds16(Brow1, &Bs[0][s_b0 + 2048]);

    for (int i = 0; i < T; ++i) {
        __syncthreads();
        const int cur = i & 1;
        if (i + 1 < T) {
            const int nb = cur ^ 1;
            const int ko = (i + 1) << 5;
            gload_lds16(Arow0 + ko, &As[nb][s_b0]);
            gload_lds16(Arow1 + ko, &As[nb][s_b0 + 2048]);
            gload_lds16(Brow0 + ko, &Bs[nb][s_b0]);
            gload_lds16(Brow1 + ko, &Bs[nb][s_b0 + 2048]);
        }
        bf16x8 af[4], bg[4];
        #pragma unroll
        for (int j = 0; j < 4; ++j) {
            af[j] = *(const bf16x8*)&As[cur][(wm + j * 16 + fr) * 32 + qsw];
            bg[j] = *(const bf16x8*)&Bs[cur][(wn + j * 16 + fr) * 32 + qsw];
        }
        #pragma unroll
        for (int mi = 0; mi < 4; ++mi)
            #pragma unroll
            for (int ni = 0; ni < 4; ++ni)
                acc[mi][ni] = __builtin_amdgcn_mfma_f32_16x16x32_bf16(
                    af[mi], bg[ni], acc[mi][ni], 0, 0, 0);
    }

    #pragma unroll
    for (int mi = 0; mi < 4; ++mi) {
        #pragma unroll
        for (int i = 0; i < 4; ++i) {
            int rm = row0 + wm + mi * 16 + qd * 4 + i;
            if (rm >= M) continue;
            #pragma unroll
            for (int ni = 0; ni < 4; ++ni) {
                int cn = col0 + wn + ni * 16 + fr;
                if (cn >= N) continue;
                gemm_epi(acc[mi][ni][i] * scale, rm, cn, epi, Cf, ldc, Cb, ldcb, bias);
            }
        }
    }
}

template<int EPI>
__global__ __launch_bounds__(256, 4)
void bgemm(const u16* __restrict__ A, int lda,
           const u16* __restrict__ Bm, int ldb,
           int M, int N, int K, float scale,
           float* __restrict__ Cf, int ldc,
           u16* __restrict__ Cb, int ldcb,
           const float* __restrict__ bias,
           int nxt, int swiz)
{
    gemm_body4(A, lda, Bm, ldb, M, N, K, scale, Cf, ldc, Cb, ldcb, bias,
               nxt, swiz, EPI, blockIdx.x);
}

// ---------------------------------------------------------------------------
// 256x256 phased GEMM body (round-3/5 measured: FFN2 ~95-97 µs, conflicts 0):
// 512 threads = 8 waves (2M x 4N), wave owns 128x64. BK=32, ring of FOUR
// K-tile LDS slots (128 KiB, 1 block/CU), counted-vmcnt. FFN2 only.
// ---------------------------------------------------------------------------
__device__ __forceinline__ void gemm256_body(
    const u16* __restrict__ A, int lda,
    const u16* __restrict__ Bm, int ldb,
    int M, int N, int K, float scale,
    float* __restrict__ Cf, int ldc,
    u16* __restrict__ Cb, int ldcb,
    const float* __restrict__ bias,
    int nxt, int epi, int id)
{
    __shared__ __align__(16) u16 As[4][8192];
    __shared__ __align__(16) u16 Bs[4][8192];
    const int tid = threadIdx.x;
    const int bx = id % nxt, by = id / nxt;
    const int row0 = by << 8, col0 = bx << 8;
    const int lane = tid & 63, wv = tid >> 6;
    const int wm = (wv >> 2) << 7;         // 0 / 128
    const int wn = (wv & 3) << 6;          // 0 / 64 / 128 / 192
    const int fr = lane & 15, qd = lane >> 4;

    // fragment LDS offsets (u16 units), read-side swizzle
    int aoff[8], boff[4];
    #pragma unroll
    for (int mi = 0; mi < 8; ++mi) {
        int r = wm + mi * 16 + fr;
        aoff[mi] = r * 32 + ((qd ^ ((r >> 1) & 3)) << 3);
    }
    #pragma unroll
    for (int ni = 0; ni < 4; ++ni) {
        int r = wn + ni * 16 + fr;
        boff[ni] = r * 32 + ((qd ^ ((r >> 1) & 3)) << 3);
    }

    // staging: chunk i (0..1023) -> linear LDS byte i*16; LDS base passed to
    // gload_lds is WAVE-UNIFORM (wv*512 u16); global source pre-swizzled so
    // linear LDS + swizzled read round-trips (rule #21).
    const int i0 = tid, i1 = 512 + tid;
    const int r0 = i0 >> 2, r1 = i1 >> 2;
    const int c0 = ((i0 & 3) ^ ((r0 >> 1) & 3)) << 3;
    const int c1 = ((i1 & 3) ^ ((r1 >> 1) & 3)) << 3;
    const u16* Ag0 = A  + (size_t)(row0 + r0) * lda + c0;
    const u16* Ag1 = A  + (size_t)(row0 + r1) * lda + c1;
    const u16* Bg0 = Bm + (size_t)(col0 + r0) * ldb + c0;
    const u16* Bg1 = Bm + (size_t)(col0 + r1) * ldb + c1;
    const int lb0 = wv * 512;                      // u16, wave-uniform
    const int lb1 = 4096 + wv * 512;               // u16, wave-uniform

    f32x4 acc[8][4] = {};
    const int T = K >> 5;                   // K multiple of 32, T >= 4

    // prologue: stage tiles 0,1,2 into slots 0,1,2
    #pragma unroll
    for (int p = 0; p < 3; ++p) {
        const int ko = p << 5;
        gload_lds16(Ag0 + ko, &As[p][lb0]);
        gload_lds16(Ag1 + ko, &As[p][lb1]);
        gload_lds16(Bg0 + ko, &Bs[p][lb0]);
        gload_lds16(Bg1 + ko, &Bs[p][lb1]);
    }
    __builtin_amdgcn_sched_barrier(0);
    asm volatile("s_waitcnt vmcnt(8)");            // tile 0 landed (this wave)
    __builtin_amdgcn_sched_barrier(0);
    __builtin_amdgcn_s_barrier();                  // ... in all waves
    __builtin_amdgcn_sched_barrier(0);

    for (int t = 0; t < T; ++t) {
        const int slot = t & 3;
        const u16* as = &As[slot][0];
        const u16* bs = &Bs[slot][0];
        const int ns = (t + 3) & 3;
        const int ko = (t + 3) << 5;
        const bool pf = (t + 3 < T);

        // ---- phase A: A-frags + B n-half 0 ----
        bf16x8 a[8];
        #pragma unroll
        for (int mi = 0; mi < 8; ++mi)
            a[mi] = *(const bf16x8*)(as + aoff[mi]);
        bf16x8 b0 = *(const bf16x8*)(bs + boff[0]);
        bf16x8 b1 = *(const bf16x8*)(bs + boff[1]);
        if (pf) {
            gload_lds16(Ag0 + ko, &As[ns][lb0]);
            gload_lds16(Ag1 + ko, &As[ns][lb1]);
        }
        __builtin_amdgcn_sched_barrier(0);
        __builtin_amdgcn_s_barrier();
        __builtin_amdgcn_sched_barrier(0);
        __builtin_amdgcn_s_setprio(1);
        #pragma unroll
        for (int mi = 0; mi < 8; ++mi) {
            acc[mi][0] = __builtin_amdgcn_mfma_f32_16x16x32_bf16(
                a[mi], b0, acc[mi][0], 0, 0, 0);
            acc[mi][1] = __builtin_amdgcn_mfma_f32_16x16x32_bf16(
                a[mi], b1, acc[mi][1], 0, 0, 0);
        }
        __builtin_amdgcn_s_setprio(0);
        __builtin_amdgcn_sched_barrier(0);
        __builtin_amdgcn_s_barrier();
        __builtin_amdgcn_sched_barrier(0);

        // ---- phase B: B n-half 1 (A-frags reused) ----
        bf16x8 b2 = *(const bf16x8*)(bs + boff[2]);
        bf16x8 b3 = *(const bf16x8*)(bs + boff[3]);
        if (pf) {
            gload_lds16(Bg0 + ko, &Bs[ns][lb0]);
            gload_lds16(Bg1 + ko, &Bs[ns][lb1]);
        }
        __builtin_amdgcn_sched_barrier(0);
        if (t < T - 3) asm volatile("s_waitcnt vmcnt(8)");
        else           asm volatile("s_waitcnt vmcnt(0)");
        __builtin_amdgcn_sched_barrier(0);
        __builtin_amdgcn_s_barrier();
        __builtin_amdgcn_sched_barrier(0);
        __builtin_amdgcn_s_setprio(1);
        #pragma unroll
        for (int mi = 0; mi < 8; ++mi) {
            acc[mi][2] = __builtin_amdgcn_mfma_f32_16x16x32_bf16(
                a[mi], b2, acc[mi][2], 0, 0, 0);
            acc[mi][3] = __builtin_amdgcn_mfma_f32_16x16x32_bf16(
                a[mi], b3, acc[mi][3], 0, 0, 0);
        }
        __builtin_amdgcn_s_setprio(0);
        __builtin_amdgcn_sched_barrier(0);
        __builtin_amdgcn_s_barrier();
        __builtin_amdgcn_sched_barrier(0);   // pin: no next-slot reads hoist
    }

    #pragma unroll
    for (int mi = 0; mi < 8; ++mi) {
        #pragma unroll
        for (int i = 0; i < 4; ++i) {
            int rm = row0 + wm + mi * 16 + qd * 4 + i;
            if (rm >= M) continue;
            #pragma unroll
            for (int ni = 0; ni < 4; ++ni) {
                int cn = col0 + wn + ni * 16 + fr;
                if (cn >= N) continue;
                gemm_epi(acc[mi][ni][i] * scale, rm, cn, epi, Cf, ldc, Cb, ldcb, bias);
            }
        }
    }
}

template<int EPI>
__global__ __launch_bounds__(512, 2)
void bgemm256(const u16* __restrict__ A, int lda,
              const u16* __restrict__ Bm, int ldb,
              int M, int N, int K, float scale,
              float* __restrict__ Cf, int ldc,
              u16* __restrict__ Cb, int ldcb,
              const float* __restrict__ bias,
              int nxt)
{
    // bijective XCD swizzle (grid is a multiple of 8)
    const int g8 = (int)gridDim.x >> 3;
    const int id = (int)blockIdx.x;
    const int w = (id & 7) * g8 + (id >> 3);
    gemm256_body(A, lda, Bm, ldb, M, N, K, scale, Cf, ldc, Cb, ldcb, bias,
                 nxt, EPI, w);
}

// 8-wave 512-thread body — used ONLY inside kern_mix (small GEMMs).
// Round-8: REVERTED to the round-6 non-split body. Round-7's split-K variant
// needed 64 KiB LDS, which throttled ALL kern_mix paths (esp. mix2's 3328
// cast-transpose blocks: 6 -> 2 blocks/CU) and regressed +25 µs end-to-end.
// T2 swizzle retained (same algebra as gemm_body4).
__device__ __forceinline__ void gemm_body8(
    const u16* __restrict__ A, int lda,
    const u16* __restrict__ Bm, int ldb,
    int M, int N, int K, float scale,
    float* __restrict__ Cf, int ldc,
    u16* __restrict__ Cb, int ldcb,
    const float* __restrict__ bias,
    int nxt, int swiz, int epi, int id)
{
    __shared__ __align__(16) u16 As[2][128 * 32];
    __shared__ __align__(16) u16 Bs[2][128 * 32];
    const int tid = threadIdx.x;
    int bx, by;
    if (swiz) { int r8 = id & 7; int q = id >> 3; bx = q % nxt; by = (q / nxt) * 8 + r8; }
    else      { bx = id % nxt; by = id / nxt; }
    const int row0 = by * 128, col0 = bx * 128;
    const int lane = tid & 63, wv = tid >> 6;          // wv 0..7
    const int wm = (wv >> 1) * 32, wn = (wv & 1) * 64; // wave = 32x64
    const int fr = lane & 15, qd = lane >> 4;

    const int s_b0  = wv * 512;
    const int s_row = tid >> 2;
    const int s_sw  = ((tid & 3) ^ ((tid >> 3) & 3)) * 8;   // swizzled src slot
    const u16* Arow = A  + (size_t)(row0 + s_row) * lda + s_sw;
    const u16* Brow = Bm + (size_t)(col0 + s_row) * ldb + s_sw;
    const int qsw = (qd ^ ((fr >> 1) & 3)) * 8;             // swizzled read slot

    f32x4 acc[2][4] = {};

    const int T = K >> 5;
    gload_lds16(Arow, &As[0][s_b0]);
    gload_lds16(Brow, &Bs[0][s_b0]);

    for (int i = 0; i < T; ++i) {
        __syncthreads();
        const int cur = i & 1;
        if (i + 1 < T) {
            const int ko = (i + 1) << 5;
            gload_lds16(Arow + ko, &As[cur ^ 1][s_b0]);
            gload_lds16(Brow + ko, &Bs[cur ^ 1][s_b0]);
        }
        bf16x8 af[2], bg[4];
        #pragma unroll
        for (int j = 0; j < 2; ++j)
            af[j] = *(const bf16x8*)&As[cur][(wm + j * 16 + fr) * 32 + qsw];
        #pragma unroll
        for (int j = 0; j < 4; ++j)
            bg[j] = *(const bf16x8*)&Bs[cur][(wn + j * 16 + fr) * 32 + qsw];
        #pragma unroll
        for (int mi = 0; mi < 2; ++mi)
            #pragma unroll
            for (int ni = 0; ni < 4; ++ni)
                acc[mi][ni] = __builtin_amdgcn_mfma_f32_16x16x32_bf16(
                    af[mi], bg[ni], acc[mi][ni], 0, 0, 0);
    }

    #pragma unroll
    for (int mi = 0; mi < 2; ++mi) {
        #pragma unroll
        for (int i = 0; i < 4; ++i) {
            int rm = row0 + wm + mi * 16 + qd * 4 + i;
            if (rm >= M) continue;
            #pragma unroll
            for (int ni = 0; ni < 4; ++ni) {
                int cn = col0 + wn + ni * 16 + fr;
                if (cn >= N) continue;
                gemm_epi(acc[mi][ni][i] * scale, rm, cn, epi, Cf, ldc, Cb, ldcb, bias);
            }
        }
    }
}

// ---------------------------------------------------------------------------
// Mixed launch: grouped small GEMMs + cast-transpose tiles + PARALLEL
// adjacency in one 512-thread dispatch.
// ---------------------------------------------------------------------------
struct GDesc {
    const u16* A; const u16* B; float* Cf; u16* Cb; const float* bias;
    int lda, ldb, ldc, ldcb, M, N, K, epi, nxt, swiz, blk0;
    float scale;
};
struct TDesc { const float* src; u16* dst; int srs, drs, rows, cols, padrows, rt, nblk; };
struct MPack { GDesc g[3]; TDesc t[2]; const int* ei; float* Adj; int ng, gtot, nt; };

// Coalesced LDS-tiled cast-transpose tile (512 threads: 32x16, 2 rows each).
__device__ __forceinline__ void castT_body(TDesc T, int id)
{
    __shared__ float t[32][33];
    const int bx = id % T.rt, by = id / T.rt;
    const int r0 = bx * 32, c0 = by * 32;
    const int tx = threadIdx.x & 31, ty = threadIdx.x >> 5;   // ty 0..15
    #pragma unroll
    for (int k = 0; k < 2; ++k) {
        int r = r0 + ty + k * 16, c = c0 + tx;
        t[ty + k * 16][tx] = (r < T.rows && c < T.cols) ? T.src[(size_t)r * T.srs + c] : 0.f;
    }
    __syncthreads();
    #pragma unroll
    for (int k = 0; k < 2; ++k) {
        int c = c0 + ty + k * 16, r = r0 + tx;
        if (c < T.cols && r < T.padrows)
            T.dst[(size_t)c * T.drs + r] = f2bf(t[tx][ty + k * 16]);
    }
}

// PARALLEL dense 14x14 GCN adjacency + colw.
__device__ __forceinline__ void adj_body(const int* __restrict__ ei, float* __restrict__ Adj)
{
    __shared__ float degS[NN_], dinvS[NN_], adjS[NN_ * NN_];
    const int tid = threadIdx.x;
    if (tid < NN_) degS[tid] = 1.f;
    if (tid < NN_ * NN_) adjS[tid] = 0.f;
    __syncthreads();
    int s = 0, d = 0;
    if (tid < EE_) { s = ei[tid]; d = ei[EE_ + tid]; atomicAdd(&degS[d], 1.f); }
    __syncthreads();
    if (tid < NN_) dinvS[tid] = rsqrtf(degS[tid]);
    __syncthreads();
    if (tid < EE_) atomicAdd(&adjS[d * NN_ + s], dinvS[s] * dinvS[d]);
    if (tid < NN_) atomicAdd(&adjS[tid * NN_ + tid], dinvS[tid] * dinvS[tid]);
    __syncthreads();
    if (tid < NN_ * NN_) Adj[tid] = adjS[tid];
    if (tid < 16) {
        float sum = 0.f;
        if (tid < NN_)
            for (int j = 0; j < NN_; ++j) sum += adjS[j * NN_ + tid];
        Adj[NN_ * NN_ + tid] = sum / (float)NN_;
    }
}

__global__ __launch_bounds__(512, 6)
void kern_mix(MPack p)
{
    int id = blockIdx.x;
    if (id < p.gtot) {
        int si = 0;
        for (int s = 1; s < p.ng; ++s) if (id >= p.g[s].blk0) si = s;
        GDesc D = p.g[si];
        gemm_body8(D.A, D.lda, D.B, D.ldb, D.M, D.N, D.K, D.scale,
                   D.Cf, D.ldc, D.Cb, D.ldcb, D.bias, D.nxt, D.swiz, D.epi,
                   id - D.blk0);
        return;
    }
    id -= p.gtot;
    for (int s = 0; s < p.nt; ++s) {
        if (id < p.t[s].nblk) { castT_body(p.t[s], id); return; }
        id -= p.t[s].nblk;
    }
    if (id == 0 && p.ei) adj_body(p.ei, p.Adj);
}

// Multi-segment fp32->bf16 cast (+ zero-fill segments with scols=0).
struct CDesc { const float* src; u16* dst; int srs, drs, dcols, scols; };
struct CPack { CDesc d[9]; unsigned cum[10]; int n; };

__global__ void kern_mcast(CPack p)
{
    unsigned idx = blockIdx.x * 256 + threadIdx.x;
    int si = -1;
    for (int s = 0; s < p.n; ++s)
        if (idx >= p.cum[s] && idx < p.cum[s + 1]) { si = s; break; }
    if (si < 0) return;
    CDesc D = p.d[si];
    unsigned k = idx - p.cum[si];
    int r = k / D.dcols, c = k - r * D.dcols;
    D.dst[(size_t)r * D.drs + c] =
        (c < D.scols) ? f2bf(D.src[(size_t)r * D.srs + c]) : (u16)0;
}

// Fused [ew rowmax+exp] + exp(S0) + G + Z.
__global__ __launch_bounds__(256) void kern_eG(const float* __restrict__ S,
    u16* __restrict__ Gb, float* __restrict__ Z)
{
    __shared__ float red[256];
    __shared__ u16 ews[NN_ * 1024];   // 28.7 KB
    const int l = blockIdx.x, tid = threadIdx.x;
    const int lane = tid & 63, wv = tid >> 6;

    const float* wraw = S + 1024 * 1024;
    for (int z = wv; z < NN_; z += 4) {
        const float* r = wraw + z * 1024;
        float vv[16], mx = -1e30f;
        #pragma unroll
        for (int j = 0; j < 16; ++j) { vv[j] = r[lane + 64 * j]; mx = fmaxf(mx, vv[j]); }
        #pragma unroll
        for (int off = 32; off > 0; off >>= 1) mx = fmaxf(mx, __shfl_down(mx, off));
        mx = __shfl(mx, 0);
        #pragma unroll
        for (int j = 0; j < 16; ++j)
            ews[z * 1024 + lane + 64 * j] = f2bf(expf(vv[j] - mx));
    }
    const float* row = S + (size_t)l * 1024;
    float m = -1e30f;
    #pragma unroll
    for (int k = 0; k < 4; ++k) m = fmaxf(m, row[tid + 256 * k]);
    red[tid] = m; __syncthreads();          // also publishes ews
    for (int s = 128; s > 0; s >>= 1) {
        if (tid < s) red[tid] = fmaxf(red[tid], red[tid + s]);
        __syncthreads();
    }
    m = red[0];
    float ev[16];
    #pragma unroll
    for (int j = 0; j < 16; ++j) ev[j] = expf(row[lane + 64 * j] - m);
    u16* gr = Gb + (size_t)l * NN_ * 1024;
    for (int z = wv; z < NN_; z += 4) {
        const u16* er = &ews[z * 1024];
        float s = 0.f;
        #pragma unroll
        for (int j = 0; j < 16; ++j) {
            float pv = ev[j] * bf2f(er[lane + 64 * j]);
            gr[(size_t)z * 1024 + lane + 64 * j] = f2bf(pv);
            s += pv;
        }
        #pragma unroll
        for (int off = 32; off > 0; off >>= 1) s += __shfl_down(s, off);
        if (lane == 0) Z[l * NN_ + z] = s;
    }
}

// x1 = LN1(node + Pb + co); Pb is bf16 attn-out already scaled by 1/Z.
// Vectorized (G13, round-7): float4/short4 loads (Pb rows 8B-aligned,
// co/img/word 16B), short8 stores (X1b rows 16B); values kept in registers
// across the two reduction passes.
__global__ __launch_bounds__(256) void kern_ln1(
    const float* __restrict__ img, const float* __restrict__ word,
    const u16* __restrict__ Pb,
    const float* __restrict__ co, const float* __restrict__ g,
    const float* __restrict__ bta, u16* __restrict__ Xb)
{
    __shared__ float buf[816];
    __shared__ float red[256];
    __shared__ float stats[2];
    int row = blockIdx.x;
    int b = row / NN_, n = row - b * NN_;
    const u16* pr = Pb + (size_t)row * DD_;
    const float* cr = co + n * DD_;
    const int t = threadIdx.x;
    float v0 = 0.f, v1 = 0.f, v2 = 0.f, v3 = 0.f;
    float s = 0.f;
    if (t < 203) {                         // 203*4 = 812 = DD_
        const int d = t * 4;
        float4 iv = (d < IMG_) ? *(const float4*)&img[(size_t)b * IMG_ + d]
                               : *(const float4*)&word[n * TXT_ + (d - IMG_)];
        u16x4 pv = *(const u16x4*)&pr[d];
        float4 cv = *(const float4*)&cr[d];
        v0 = iv.x + bf2f(pv[0]) + cv.x;
        v1 = iv.y + bf2f(pv[1]) + cv.y;
        v2 = iv.z + bf2f(pv[2]) + cv.z;
        v3 = iv.w + bf2f(pv[3]) + cv.w;
        buf[d] = v0; buf[d + 1] = v1; buf[d + 2] = v2; buf[d + 3] = v3;
        s = v0 + v1 + v2 + v3;
    }
    red[t] = s; __syncthreads();
    for (int k = 128; k > 0; k >>= 1) {
        if (t < k) red[t] += red[t + k];
        __syncthreads();
    }
    if (t == 0) stats[0] = red[0] / DD_;
    __syncthreads();
    float mu = stats[0];
    float s2 = 0.f;
    if (t < 203) {
        float a0 = v0 - mu, a1 = v1 - mu, a2 = v2 - mu, a3 = v3 - mu;
        s2 = a0 * a0 + a1 * a1 + a2 * a2 + a3 * a3;
    }
    red[t] = s2; __syncthreads();
    for (int k = 128; k > 0; k >>= 1) {
        if (t < k) red[t] += red[t + k];
        __syncthreads();
    }
    if (t == 0) stats[1] = rsqrtf(red[0] / DD_ + 1e-5f);
    __syncthreads();
    float rstd = stats[1];
    u16* xb = Xb + (size_t)row * KP_;
    if (t < 104) {                          // 104*8 = 832 = KP_ (incl pad)
        const int d = t * 8;
        u16x8 o;
        #pragma unroll
        for (int k = 0; k < 8; ++k) {
            int dd = d + k;
            o[k] = (dd < DD_)
                 ? f2bf((buf[dd] - mu) * rstd * g[dd] + bta[dd]) : (u16)0;
        }
        *(u16x8*)&xb[d] = o;
    }
}

// ---------------------------------------------------------------------------
// Fused LN2 + GCN1 + GCN2 + mean-pool + linear. One block per image b.
// ---------------------------------------------------------------------------
#define X2S_ 840
#define G1S_ 136
__global__ __launch_bounds__(256, 4)
void kern_gcn(const u16* __restrict__ Yb,
              const float* __restrict__ g2v, const float* __restrict__ bt2,
              const u16* __restrict__ Wg1T, const float* __restrict__ bg1,
              const u16* __restrict__ Wg2T, const float* __restrict__ bg2,
              const float* __restrict__ Wl,  const float* __restrict__ bl,
              const float* __restrict__ AdjW, float* __restrict__ out)
{
    __shared__ __align__(16) u16 x2s[16 * X2S_];      // 26.9 KB; g1s overlays
    __shared__ __align__(16) float h1s[16 * 132];     // 8.4 KB
    __shared__ float adj_s[NN_ * NN_];
    __shared__ float colw_s[16];
    __shared__ float pool_s[HID_];
    u16* g1s = x2s;                                   // overlay (16*G1S_ u16)
    const int b = blockIdx.x, tid = threadIdx.x;
    const int lane = tid & 63, wv = tid >> 6;
    const int fr = lane & 15, qd = lane >> 4;

    if (tid < NN_ * NN_) adj_s[tid] = AdjW[tid];
    if (tid >= NN_ * NN_ && tid < NN_ * NN_ + 16) colw_s[tid - NN_ * NN_] = AdjW[tid];
    for (int k = tid; k < 2 * X2S_; k += 256) x2s[14 * X2S_ + k] = 0;
    for (int k = tid; k < 14 * (X2S_ - DD_); k += 256) {
        int j = k / (X2S_ - DD_), c = k - j * (X2S_ - DD_);
        x2s[j * X2S_ + DD_ + c] = 0;
    }

    // --- LN2 per node row ---
    for (int j = wv; j < NN_; j += 4) {
        const u16* yr = Yb + (size_t)(b * NN_ + j) * KP_;
        float vv[13], s = 0.f;
        #pragma unroll
        for (int k = 0; k < 13; ++k) {
            int d = lane + 64 * k;
            float v = (d < DD_) ? bf2f(yr[d]) : 0.f;
            vv[k] = v; s += v;
        }
        #pragma unroll
        for (int off = 32; off > 0; off >>= 1) s += __shfl_down(s, off);
        s = __shfl(s, 0);
        float mu = s / (float)DD_, s2 = 0.f;
        #pragma unroll
        for (int k = 0; k < 13; ++k) {
            int d = lane + 64 * k;
            float t = (d < DD_) ? vv[k] - mu : 0.f;
            s2 += t * t;
        }
        #pragma unroll
        for (int off = 32; off > 0; off >>= 1) s2 += __shfl_down(s2, off);
        s2 = __shfl(s2, 0);
        float rstd = rsqrtf(s2 / (float)DD_ + 1e-5f);
        #pragma unroll
        for (int k = 0; k < 13; ++k) {
            int d = lane + 64 * k;
            if (d < DD_)
                x2s[j * X2S_ + d] = f2bf((vv[k] - mu) * rstd * g2v[d] + bt2[d]);
        }
    }
    __syncthreads();

    // --- GCN1 (MFMA, M=16, K=KP_) ---
    {
        f32x4 acc[2] = {{}, {}};
        const u16* wp0 = Wg1T + (size_t)(wv * 32 + fr) * KP_ + qd * 8;
        const u16* wp1 = wp0 + (size_t)16 * KP_;
        bf16x8 bc0 = *(const bf16x8*)wp0;
        bf16x8 bc1 = *(const bf16x8*)wp1;
        for (int k0 = 0; k0 < KP_; k0 += 32) {
            bf16x8 bn0 = bc0, bn1 = bc1;
            if (k0 + 32 < KP_) {
                bn0 = *(const bf16x8*)(wp0 + k0 + 32);
                bn1 = *(const bf16x8*)(wp1 + k0 + 32);
            }
            bf16x8 af = *(const bf16x8*)&x2s[fr * X2S_ + k0 + qd * 8];
            acc[0] = __builtin_amdgcn_mfma_f32_16x16x32_bf16(af, bc0, acc[0], 0, 0, 0);
            acc[1] = __builtin_amdgcn_mfma_f32_16x16x32_bf16(af, bc1, acc[1], 0, 0, 0);
            bc0 = bn0; bc1 = bn1;
        }
        #pragma unroll
        for (int t = 0; t < 2; ++t)
            #pragma unroll
            for (int i = 0; i < 4; ++i)
                h1s[(qd * 4 + i) * 132 + wv * 32 + t * 16 + fr] = acc[t][i];
    }
    __syncthreads();   // x2s dead; g1s overlay now writable

    // --- G1 = relu(Adj @ H1 + bg1) -> bf16; zero pad rows 14,15 ---
    {
        const int f = tid & 127, jj = (tid >> 7) * 7;
        #pragma unroll
        for (int j = 0; j < 7; ++j) {
            float s = bg1[f];
            #pragma unroll
            for (int i = 0; i < NN_; ++i)
                s = fmaf(adj_s[(jj + j) * NN_ + i], h1s[i * 132 + f], s);
            g1s[(jj + j) * G1S_ + f] = f2bf(s > 0.f ? s : 0.f);
        }
        for (int k = tid; k < 2 * G1S_; k += 256) g1s[14 * G1S_ + k] = 0;
    }
    __syncthreads();

    // --- GCN2 (MFMA, K=128) + pool = relu(colw·H2 + bg2) ---
    {
        f32x4 acc[2] = {{}, {}};
        const u16* wp0 = Wg2T + (size_t)(wv * 32 + fr) * HID_ + qd * 8;
        const u16* wp1 = wp0 + (size_t)16 * HID_;
        bf16x8 bc0 = *(const bf16x8*)wp0;
        bf16x8 bc1 = *(const bf16x8*)wp1;
        for (int k0 = 0; k0 < HID_; k0 += 32) {
            bf16x8 bn0 = bc0, bn1 = bc1;
            if (k0 + 32 < HID_) {
                bn0 = *(const bf16x8*)(wp0 + k0 + 32);
                bn1 = *(const bf16x8*)(wp1 + k0 + 32);
            }
            bf16x8 af = *(const bf16x8*)&g1s[fr * G1S_ + k0 + qd * 8];
            acc[0] = __builtin_amdgcn_mfma_f32_16x16x32_bf16(af, bc0, acc[0], 0, 0, 0);
            acc[1] = __builtin_amdgcn_mfma_f32_16x16x32_bf16(af, bc1, acc[1], 0, 0, 0);
            bc0 = bn0; bc1 = bn1;
        }
        #pragma unroll
        for (int t = 0; t < 2; ++t) {
            float s = 0.f;
            #pragma unroll
            for (int i = 0; i < 4; ++i) s += colw_s[qd * 4 + i] * acc[t][i];
            s += __shfl_xor(s, 16);
            s += __shfl_xor(s, 32);
            if (qd == 0) {
                int f = wv * 32 + t * 16 + fr;
                float p = s + bg2[f];
                pool_s[f] = p > 0.f ? p : 0.f;
            }
        }
    }
    __syncthreads();

    // --- out = pool @ Wl + bl ---
    if (tid < CC_) {
        float s = bl[tid];
        #pragma unroll 8
        for (int f = 0; f < HID_; ++f)
            s = fmaf(pool_s[f], Wl[(size_t)f * CC_ + tid], s);
        out[(size_t)b * CC_ + tid] = s;
    }
}

extern "C" void kernel_launch(void* const* d_in, const int* in_sizes, int n_in,
                              void* d_out, int out_size, void* d_ws, size_t ws_size,
                              hipStream_t stream)
{
    const float* img  = (const float*)d_in[0];
    const float* word = (const float*)d_in[1];
    const int*   ei   = (const int*)d_in[2];
    const float* Wi   = (const float*)d_in[3];
    const float* bi   = (const float*)d_in[4];
    const float* Wo   = (const float*)d_in[5];
    const float* bo   = (const float*)d_in[6];
    const float* g1   = (const float*)d_in[7];
    const float* bt1  = (const float*)d_in[8];
    const float* g2   = (const float*)d_in[9];
    const float* bt2  = (const float*)d_in[10];
    const float* W1   = (const float*)d_in[11];
    const float* bf1  = (const float*)d_in[12];
    const float* W2   = (const float*)d_in[13];
    const float* bf2  = (const float*)d_in[14];
    const float* Wg1  = (const float*)d_in[15];
    const float* bg1  = (const float*)d_in[16];
    const float* Wg2  = (const float*)d_in[17];
    const float* bg2  = (const float*)d_in[18];
    const float* Wl   = (const float*)d_in[19];
    const float* bl   = (const float*)d_in[20];
    float* out = (float*)d_out;

    char* ws = (char*)d_ws;
    u16*   imgb = (u16*)  (ws + OFF_IMGB);
    u16*   Wib  = (u16*)  (ws + OFF_WIB);
    u16*   wordb= (u16*)  (ws + OFF_WORDB);
    u16*   WiTX = (u16*)  (ws + OFF_WITX);
    u16*   Gb   = (u16*)  (ws + OFF_GB);
    float* Ebuf = (float*)(ws + OFF_EBUF);
    u16*   AvoT = (u16*)  (ws + OFF_AVOT);
    u16*   Wob  = (u16*)  (ws + OFF_WOB);
    u16*   Hb   = (u16*)  (ws + OFF_HB);
    u16*   Pb   = (u16*)  (ws + OFF_PB);
    u16*   X1b  = (u16*)  (ws + OFF_X1B);
    u16*   Yb   = (u16*)  (ws + OFF_YB);
    u16*   W1T  = (u16*)  (ws + OFF_W1T);
    u16*   W2T  = (u16*)  (ws + OFF_W2T);
    u16*   Aqb  = (u16*)  (ws + OFF_AQB);
    u16*   Akb  = Aqb + AROWS_ * KP_;
    u16*   Avb  = Aqb + 2 * AROWS_ * KP_;
    u16*   Tvb  = (u16*)  (ws + OFF_TVB);
    float* co   = (float*)(ws + OFF_CO);
    float* Zb   = (float*)(ws + OFF_Z);
    float* Adj  = (float*)(ws + OFF_ADJ);
    u16*   Wg1T = (u16*)  (ws + OFF_WG1T);
    u16*   Wg2T = (u16*)  (ws + OFF_WG2T);

    const float scl = 1.0f / sqrtf((float)DD_);

    // --- launch 1: multi-cast (input casts + all K-pad zeroing) ---
    {
        CPack p; p.n = 9;
        unsigned c = 0;
        auto seg = [&](int i, const float* s, int srs, u16* d, int drs,
                       int rows, int dcols, int scols) {
            p.d[i] = { s, d, srs, drs, dcols, scols };
            p.cum[i] = c; c += (unsigned)rows * dcols;
        };
        seg(0, img,        IMG_, imgb,  IMG_, B_,   IMG_, IMG_);
        seg(1, Wi,         DD_,  Wib,   IMG_, D3_,  IMG_, IMG_);
        seg(2, word,       TXT_, wordb, TXP_, NN_,  TXP_, TXT_);
        seg(3, Wi + IMG_,  DD_,  WiTX,  TXP_, D3_,  TXP_, TXT_);
        seg(4, Wo,         DD_,  Wob,   KP_,  DD_,  KP_,  DD_);
        seg(5, nullptr, 0, Aqb + DD_,                    KP_, 1038, 20, 0); // Aq + Tq rows
        seg(6, nullptr, 0, Aqb + AROWS_ * KP_ + DD_,     KP_, 1024, 20, 0);
        seg(7, nullptr, 0, Aqb + 2 * AROWS_ * KP_ + DD_, KP_, 1024, 20, 0);
        seg(8, nullptr, 0, Tvb + DD_,                    KP_, NN_,  20, 0); // Tvb pads
        p.cum[9] = c;
        kern_mcast<<<(c + 255) / 256, 256, 0, stream>>>(p);
    }

    // --- launch 2 (mix1): T epi8 + A-proj || Wg1T/Wg2T transposes || adj ---
    {
        MPack p{};
        p.ng = 2; p.gtot = 180;
        p.g[0] = { wordb, WiTX, (float*)Tvb, Aqb, bi,
                   TXP_, TXP_, 0, 0, NN_, D3_, TXP_, 8, 20, 0, 0, 1.f };
        p.g[1] = { imgb, Wib, nullptr, Aqb, nullptr,
                   IMG_, IMG_, 0, 0, B_, D3_, IMG_, 4, 20, 1, 20, 1.f };
        p.nt = 2;
        p.t[0] = { Wg1, Wg1T, HID_, KP_,  DD_,  HID_, KP_,  26, 26 * 4 };
        p.t[1] = { Wg2, Wg2T, HID_, HID_, HID_, HID_, HID_, 4,  4 * 4 };
        p.ei = ei; p.Adj = Adj;
        kern_mix<<<180 + 104 + 16 + 1, 512, 0, stream>>>(p);
    }

    // --- launch 3 (mix2): S0+w || AvoT || co  ||  W1T/W2T transposes ---
    {
        MPack p{};
        p.ng = 3; p.gtot = 135;
        p.g[0] = { Aqb, Akb, Ebuf, nullptr, nullptr,
                   KP_, KP_, 1024, 0, 1024 + NN_, 1024, KP_, 0, 8, 0, 0, scl };
        p.g[1] = { Wob, Avb, nullptr, AvoT, nullptr,
                   KP_, KP_, 0, 1024, DD_, B_, KP_, 3, 8, 0, 72, 1.f };
        p.g[2] = { Tvb, Wob, co, nullptr, bo,
                   KP_, KP_, DD_, 0, NN_, DD_, KP_, 6, 7, 0, 128, 1.f };
        p.nt = 2;
        p.t[0] = { W1, W1T, FF_, KP_, DD_, FF_, KP_, 26, 26 * 64 };
        p.t[1] = { W2, W2T, DD_, FF_, FF_, DD_, FF_, 64, 64 * 26 };
        p.ei = nullptr; p.Adj = nullptr;
        kern_mix<<<135 + 1664 + 1664, 512, 0, stream>>>(p);
    }

    // --- launch 4: fused ew-exp + exp + G + Z ---
    kern_eG<<<1024, 256, 0, stream>>>(Ebuf, Gb, Zb);

    // --- launch 5: Pb = (G @ Avo)/Z as bf16 (128^2 4-wave body, swizzled) ---
    bgemm<5><<<7 * 112, 256, 0, stream>>>(Gb, 1024, AvoT, 1024,
        BNR_, DD_, 1024, 1.f, nullptr, 0, Pb, DD_, Zb, 7, 1);

    // --- launch 6: LN1 (vectorized) ---
    kern_ln1<<<BNR_, 256, 0, stream>>>(img, word, Pb, co, g1, bt1, X1b);

    // --- launch 7: FFN1 (128^2 4-wave body, swizzled — 1792 blocks ~4/CU) ---
    bgemm<1><<<16 * 112, 256, 0, stream>>>(X1b, KP_, W1T, KP_,
        BNR_, FF_, KP_, 1.f, nullptr, 0, Hb, FF_, bf1, 16, 1);

    // --- launch 8: FFN2 (256^2 phased body — 224 blocks, 1 clean round) ---
    bgemm256<7><<<56 * 4, 512, 0, stream>>>(Hb, FF_, W2T, FF_,
        BNR_, DD_, FF_, 1.f, (float*)X1b, KP_, Yb, KP_, bf2, 4);

    // --- launch 9: fused LN2 + GCN1 + GCN2 + pool + linear ---
    kern_gcn<<<B_, 256, 0, stream>>>(Yb, g2, bt2, Wg1T, bg1, Wg2T, bg2,
                                     Wl, bl, Adj, out);
}

// Round 9
// 457.239 us; speedup vs baseline: 1.0543x; 1.0350x over previous
//
#include <hip/hip_runtime.h>
#include <math.h>

// Problem constants
#define B_    1024
#define IMG_  512
#define TXT_  300
#define NN_   14
#define FF_   2048
#define HID_  128
#define CC_   14
#define EE_   182
#define DD_   812
#define D3_   2436
#define BNR_  14336          // B_*NN_
#define KP_   832            // 812 padded to /32 (16B-aligned rows)
#define TXP_  320            // 300 padded to /32
#define AROWS_ 1152          // Aq/Ak/Av rows: 1024 data + 14 Tq + pad to tile mult

typedef __bf16 bf16x8 __attribute__((ext_vector_type(8)));
typedef float  f32x4  __attribute__((ext_vector_type(4)));
typedef unsigned short u16;

__device__ __forceinline__ u16 f2bf(float f) {
    union { float f; unsigned u; } v; v.f = f;
    unsigned r = v.u + 0x7FFFu + ((v.u >> 16) & 1u);   // RNE
    return (u16)(r >> 16);
}
__device__ __forceinline__ float bf2f(u16 h) {
    union { unsigned u; float f; } v; v.u = ((unsigned)h) << 16; return v.f;
}

// async global->LDS, 16B per lane. LDS dst = wave-uniform base + lane*16.
__device__ __forceinline__ void gload_lds16(const u16* g, u16* l) {
    __builtin_amdgcn_global_load_lds(
        (const __attribute__((address_space(1))) void*)g,
        (__attribute__((address_space(3))) void*)l, 16, 0, 0);
}

// ---------------------------------------------------------------------------
// Workspace layout (bytes), time-multiplexed overlays (audited vs launch
// timeline; garbage/NaN only reaches epilogue-masked rows/cols; K-pads of
// real rows always explicitly zeroed).
// ---------------------------------------------------------------------------
#define OFF_IMGB  0ULL              // bf16 [1024][512]
#define OFF_WIB   1048576ULL        // bf16 [2436][512]
#define OFF_WORDB 3543040ULL        // bf16 [128][320]
#define OFF_WITX  3624960ULL        // bf16 [2560][320]
#define OFF_GB    0ULL              // bf16 [14336][1024] (eG..P)
#define OFF_EBUF  29360128ULL       // f32  [1038][1024]  (S0..eG)
#define OFF_AVOT  33611776ULL       // bf16 [896][1024]   (mix2..P)
#define OFF_WOB   35446784ULL       // bf16 [896][832]    (mcast..mix2)
#define OFF_HB    0ULL              // bf16 [14336][2048] (FFN1..FFN2)
#define OFF_PB    58720256ULL       // bf16 [14336][812]  (P..ln1)
#define OFF_X1B   82001920ULL       // bf16 [14336][832]  (ln1..FFN2)
#define OFF_YB    105857024ULL      // bf16 [14336][832]  (FFN2..gcn)
#define OFF_W1T   129712128ULL      // bf16 [2048][832]   (mix2..FFN1)
#define OFF_W2T   133120000ULL      // bf16 [896][2048]   (mix2..FFN2)
#define OFF_AQB   152420352ULL      // bf16 3x[1152][832] (Aq|Ak|Av)
#define OFF_TVB   158307552ULL      // bf16 [128][832]
#define OFF_CO    158520544ULL      // f32  [14][812]
#define OFF_Z     158566016ULL      // f32  [14336]
#define OFF_ADJ   158623360ULL      // f32  [196 adj + 16 colw]
#define OFF_WG1T  158624384ULL      // bf16 [128][832]
#define OFF_WG2T  158837376ULL      // bf16 [128][128]

// ---------------------------------------------------------------------------
// 4-wave GEMM body (round-11 proven: FFN1 ~96 µs): 128x128 tile, BK=32,
// 256 threads, 2x2 waves of 64x64, 64 AGPR acc, double-buffered
// global_load_lds. Used by the big standalone bgemm launches.
// epi 0: Cf=v. 1: Cb=bf16(relu(v+bias[cn])). 2: Cf=v+bias[cn]+bf2f(Cb).
// 3: Cb=bf16(v). 4: split-3 into [Aq|Ak|Av]. 5: Cb=bf16(v/bias[rm]).
// 6: Cf=v+bias[cn]. 7: Cb=bf16(v+bias[cn]+bf2f(((u16*)Cf)[rm*ldc+cn])).
// 8: T-split: cn<812 -> Cb[(1024+rm)*KP_+cn]; cn>=1624 -> ((u16*)Cf)[rm*KP_+cn-1624].
// ---------------------------------------------------------------------------
__device__ __forceinline__ void gemm_epi(
    float v, int rm, int cn, int epi,
    float* __restrict__ Cf, int ldc, u16* __restrict__ Cb, int ldcb,
    const float* __restrict__ bias)
{
    if (epi == 0) Cf[(size_t)rm * ldc + cn] = v;
    else if (epi == 1) { v += bias[cn]; v = v > 0.f ? v : 0.f;
                    Cb[(size_t)rm * ldcb + cn] = f2bf(v); }
    else if (epi == 2) Cf[(size_t)rm * ldc + cn] =
                    v + bias[cn] + bf2f(Cb[(size_t)rm * ldcb + cn]);
    else if (epi == 3) Cb[(size_t)rm * ldcb + cn] = f2bf(v);
    else if (epi == 4) { int bs = cn / DD_, cc = cn - bs * DD_;
                    Cb[(size_t)bs * (AROWS_ * KP_) + (size_t)rm * KP_ + cc] = f2bf(v); }
    else if (epi == 5) { float invz = 1.0f / bias[rm];
                    Cb[(size_t)rm * ldcb + cn] = f2bf(v * invz); }
    else if (epi == 6) Cf[(size_t)rm * ldc + cn] = v + bias[cn];
    else if (epi == 7) { const u16* rx = (const u16*)Cf;
                    Cb[(size_t)rm * ldcb + cn] =
                        f2bf(v + bias[cn] + bf2f(rx[(size_t)rm * ldc + cn])); }
    else if (epi == 8) {
        float t = v + bias[cn];
        if (cn < DD_) Cb[(size_t)(1024 + rm) * KP_ + cn] = f2bf(t);
        else if (cn >= 2 * DD_)
            ((u16*)Cf)[(size_t)rm * KP_ + (cn - 2 * DD_)] = f2bf(t);
    }
}

__device__ __forceinline__ void gemm_body4(
    const u16* __restrict__ A, int lda,
    const u16* __restrict__ Bm, int ldb,
    int M, int N, int K, float scale,
    float* __restrict__ Cf, int ldc,
    u16* __restrict__ Cb, int ldcb,
    const float* __restrict__ bias,
    int nxt, int swiz, int epi, int id)
{
    __shared__ __align__(16) u16 As[2][128 * 32];
    __shared__ __align__(16) u16 Bs[2][128 * 32];
    const int tid = threadIdx.x;
    int bx, by;
    if (swiz) { int r8 = id & 7; int q = id >> 3; bx = q % nxt; by = (q / nxt) * 8 + r8; }
    else      { bx = id % nxt; by = id / nxt; }
    const int row0 = by * 128, col0 = bx * 128;
    const int lane = tid & 63, wv = tid >> 6;
    const int wm = (wv >> 1) * 64, wn = (wv & 1) * 64;
    const int fr = lane & 15, qd = lane >> 4;

    const int s_r0  = (wv * 64 + lane) >> 2;
    const int s_ko  = (lane & 3) * 8;
    const int s_b0  = (wv * 64) * 8;
    const u16* Arow0 = A  + (size_t)(row0 + s_r0) * lda + s_ko;
    const u16* Arow1 = A  + (size_t)(row0 + s_r0 + 64) * lda + s_ko;
    const u16* Brow0 = Bm + (size_t)(col0 + s_r0) * ldb + s_ko;
    const u16* Brow1 = Bm + (size_t)(col0 + s_r0 + 64) * ldb + s_ko;

    f32x4 acc[4][4] = {};

    const int T = K >> 5;
    gload_lds16(Arow0, &As[0][s_b0]);
    gload_lds16(Arow1, &As[0][s_b0 + 2048]);
    gload_lds16(Brow0, &Bs[0][s_b0]);
    gload_lds16(Brow1, &Bs[0][s_b0 + 2048]);

    for (int i = 0; i < T; ++i) {
        __syncthreads();
        const int cur = i & 1;
        if (i + 1 < T) {
            const int nb = cur ^ 1;
            const int ko = (i + 1) << 5;
            gload_lds16(Arow0 + ko, &As[nb][s_b0]);
            gload_lds16(Arow1 + ko, &As[nb][s_b0 + 2048]);
            gload_lds16(Brow0 + ko, &Bs[nb][s_b0]);
            gload_lds16(Brow1 + ko, &Bs[nb][s_b0 + 2048]);
        }
        bf16x8 af[4], bg[4];
        #pragma unroll
        for (int j = 0; j < 4; ++j) {
            af[j] = *(const bf16x8*)&As[cur][(wm + j * 16 + fr) * 32 + qd * 8];
            bg[j] = *(const bf16x8*)&Bs[cur][(wn + j * 16 + fr) * 32 + qd * 8];
        }
        #pragma unroll
        for (int mi = 0; mi < 4; ++mi)
            #pragma unroll
            for (int ni = 0; ni < 4; ++ni)
                acc[mi][ni] = __builtin_amdgcn_mfma_f32_16x16x32_bf16(
                    af[mi], bg[ni], acc[mi][ni], 0, 0, 0);
    }

    #pragma unroll
    for (int mi = 0; mi < 4; ++mi) {
        #pragma unroll
        for (int i = 0; i < 4; ++i) {
            int rm = row0 + wm + mi * 16 + qd * 4 + i;
            if (rm >= M) continue;
            #pragma unroll
            for (int ni = 0; ni < 4; ++ni) {
                int cn = col0 + wn + ni * 16 + fr;
                if (cn >= N) continue;
                gemm_epi(acc[mi][ni][i] * scale, rm, cn, epi, Cf, ldc, Cb, ldcb, bias);
            }
        }
    }
}

// 8-wave 512-thread body (round-12) — used ONLY inside kern_mix (small GEMMs).
__device__ __forceinline__ void gemm_body8(
    const u16* __restrict__ A, int lda,
    const u16* __restrict__ Bm, int ldb,
    int M, int N, int K, float scale,
    float* __restrict__ Cf, int ldc,
    u16* __restrict__ Cb, int ldcb,
    const float* __restrict__ bias,
    int nxt, int swiz, int epi, int id)
{
    __shared__ __align__(16) u16 As[2][128 * 32];
    __shared__ __align__(16) u16 Bs[2][128 * 32];
    const int tid = threadIdx.x;
    int bx, by;
    if (swiz) { int r8 = id & 7; int q = id >> 3; bx = q % nxt; by = (q / nxt) * 8 + r8; }
    else      { bx = id % nxt; by = id / nxt; }
    const int row0 = by * 128, col0 = bx * 128;
    const int lane = tid & 63, wv = tid >> 6;          // wv 0..7
    const int wm = (wv >> 1) * 32, wn = (wv & 1) * 64; // wave = 32x64
    const int fr = lane & 15, qd = lane >> 4;

    const int s_b0  = wv * 512;
    const int s_row = tid >> 2;
    const int s_ko  = (tid & 3) * 8;
    const u16* Arow = A  + (size_t)(row0 + s_row) * lda + s_ko;
    const u16* Brow = Bm + (size_t)(col0 + s_row) * ldb + s_ko;

    f32x4 acc[2][4] = {};

    const int T = K >> 5;
    gload_lds16(Arow, &As[0][s_b0]);
    gload_lds16(Brow, &Bs[0][s_b0]);

    for (int i = 0; i < T; ++i) {
        __syncthreads();
        const int cur = i & 1;
        if (i + 1 < T) {
            const int ko = (i + 1) << 5;
            gload_lds16(Arow + ko, &As[cur ^ 1][s_b0]);
            gload_lds16(Brow + ko, &Bs[cur ^ 1][s_b0]);
        }
        bf16x8 af[2], bg[4];
        #pragma unroll
        for (int j = 0; j < 2; ++j)
            af[j] = *(const bf16x8*)&As[cur][(wm + j * 16 + fr) * 32 + qd * 8];
        #pragma unroll
        for (int j = 0; j < 4; ++j)
            bg[j] = *(const bf16x8*)&Bs[cur][(wn + j * 16 + fr) * 32 + qd * 8];
        #pragma unroll
        for (int mi = 0; mi < 2; ++mi)
            #pragma unroll
            for (int ni = 0; ni < 4; ++ni)
                acc[mi][ni] = __builtin_amdgcn_mfma_f32_16x16x32_bf16(
                    af[mi], bg[ni], acc[mi][ni], 0, 0, 0);
    }

    #pragma unroll
    for (int mi = 0; mi < 2; ++mi) {
        #pragma unroll
        for (int i = 0; i < 4; ++i) {
            int rm = row0 + wm + mi * 16 + qd * 4 + i;
            if (rm >= M) continue;
            #pragma unroll
            for (int ni = 0; ni < 4; ++ni) {
                int cn = col0 + wn + ni * 16 + fr;
                if (cn >= N) continue;
                gemm_epi(acc[mi][ni][i] * scale, rm, cn, epi, Cf, ldc, Cb, ldcb, bias);
            }
        }
    }
}

template<int EPI>
__global__ __launch_bounds__(256, 4)
void bgemm(const u16* __restrict__ A, int lda,
           const u16* __restrict__ Bm, int ldb,
           int M, int N, int K, float scale,
           float* __restrict__ Cf, int ldc,
           u16* __restrict__ Cb, int ldcb,
           const float* __restrict__ bias,
           int nxt, int swiz)
{
    gemm_body4(A, lda, Bm, ldb, M, N, K, scale, Cf, ldc, Cb, ldcb, bias,
               nxt, swiz, EPI, blockIdx.x);
}

// ---------------------------------------------------------------------------
// Mixed launch: grouped small GEMMs + cast-transpose tiles + PARALLEL
// adjacency in one 512-thread dispatch. (Round-12 counters: serial adj_body
// = 119 µs tail at VALUBusy 0.016% — one wave crawling dependent loads.)
// ---------------------------------------------------------------------------
struct GDesc {
    const u16* A; const u16* B; float* Cf; u16* Cb; const float* bias;
    int lda, ldb, ldc, ldcb, M, N, K, epi, nxt, swiz, blk0;
    float scale;
};
struct TDesc { const float* src; u16* dst; int srs, drs, rows, cols, padrows, rt, nblk; };
struct MPack { GDesc g[3]; TDesc t[2]; const int* ei; float* Adj; int ng, gtot, nt; };

// Coalesced LDS-tiled cast-transpose tile (512 threads: 32x16, 2 rows each).
__device__ __forceinline__ void castT_body(TDesc T, int id)
{
    __shared__ float t[32][33];
    const int bx = id % T.rt, by = id / T.rt;
    const int r0 = bx * 32, c0 = by * 32;
    const int tx = threadIdx.x & 31, ty = threadIdx.x >> 5;   // ty 0..15
    #pragma unroll
    for (int k = 0; k < 2; ++k) {
        int r = r0 + ty + k * 16, c = c0 + tx;
        t[ty + k * 16][tx] = (r < T.rows && c < T.cols) ? T.src[(size_t)r * T.srs + c] : 0.f;
    }
    __syncthreads();
    #pragma unroll
    for (int k = 0; k < 2; ++k) {
        int c = c0 + ty + k * 16, r = r0 + tx;
        if (c < T.cols && r < T.padrows)
            T.dst[(size_t)c * T.drs + r] = f2bf(t[tx][ty + k * 16]);
    }
}

// PARALLEL dense 14x14 GCN adjacency + colw: edges distributed across
// threads, LDS atomics for deg/adj (182 edges, coalesced loads). Entire
// block participates (entered block-uniformly).
__device__ __forceinline__ void adj_body(const int* __restrict__ ei, float* __restrict__ Adj)
{
    __shared__ float degS[NN_], dinvS[NN_], adjS[NN_ * NN_];
    const int tid = threadIdx.x;
    if (tid < NN_) degS[tid] = 1.f;
    if (tid < NN_ * NN_) adjS[tid] = 0.f;
    __syncthreads();
    int s = 0, d = 0;
    if (tid < EE_) { s = ei[tid]; d = ei[EE_ + tid]; atomicAdd(&degS[d], 1.f); }
    __syncthreads();
    if (tid < NN_) dinvS[tid] = rsqrtf(degS[tid]);
    __syncthreads();
    if (tid < EE_) atomicAdd(&adjS[d * NN_ + s], dinvS[s] * dinvS[d]);
    if (tid < NN_) atomicAdd(&adjS[tid * NN_ + tid], dinvS[tid] * dinvS[tid]);
    __syncthreads();
    if (tid < NN_ * NN_) Adj[tid] = adjS[tid];
    if (tid < 16) {
        float sum = 0.f;
        if (tid < NN_)
            for (int j = 0; j < NN_; ++j) sum += adjS[j * NN_ + tid];
        Adj[NN_ * NN_ + tid] = sum / (float)NN_;
    }
}

__global__ __launch_bounds__(512, 6)
void kern_mix(MPack p)
{
    int id = blockIdx.x;
    if (id < p.gtot) {
        int si = 0;
        for (int s = 1; s < p.ng; ++s) if (id >= p.g[s].blk0) si = s;
        GDesc D = p.g[si];
        gemm_body8(D.A, D.lda, D.B, D.ldb, D.M, D.N, D.K, D.scale,
                   D.Cf, D.ldc, D.Cb, D.ldcb, D.bias, D.nxt, D.swiz, D.epi,
                   id - D.blk0);
        return;
    }
    id -= p.gtot;
    for (int s = 0; s < p.nt; ++s) {
        if (id < p.t[s].nblk) { castT_body(p.t[s], id); return; }
        id -= p.t[s].nblk;
    }
    if (id == 0 && p.ei) adj_body(p.ei, p.Adj);
}

// Multi-segment fp32->bf16 cast (+ zero-fill segments with scols=0).
struct CDesc { const float* src; u16* dst; int srs, drs, dcols, scols; };
struct CPack { CDesc d[9]; unsigned cum[10]; int n; };

__global__ void kern_mcast(CPack p)
{
    unsigned idx = blockIdx.x * 256 + threadIdx.x;
    int si = -1;
    for (int s = 0; s < p.n; ++s)
        if (idx >= p.cum[s] && idx < p.cum[s + 1]) { si = s; break; }
    if (si < 0) return;
    CDesc D = p.d[si];
    unsigned k = idx - p.cum[si];
    int r = k / D.dcols, c = k - r * D.dcols;
    D.dst[(size_t)r * D.drs + c] =
        (c < D.scols) ? f2bf(D.src[(size_t)r * D.srs + c]) : (u16)0;
}

// Fused [ew rowmax+exp] + exp(S0) + G + Z.
__global__ __launch_bounds__(256) void kern_eG(const float* __restrict__ S,
    u16* __restrict__ Gb, float* __restrict__ Z)
{
    __shared__ float red[256];
    __shared__ u16 ews[NN_ * 1024];   // 28.7 KB
    const int l = blockIdx.x, tid = threadIdx.x;
    const int lane = tid & 63, wv = tid >> 6;

    const float* wraw = S + 1024 * 1024;
    for (int z = wv; z < NN_; z += 4) {
        const float* r = wraw + z * 1024;
        float vv[16], mx = -1e30f;
        #pragma unroll
        for (int j = 0; j < 16; ++j) { vv[j] = r[lane + 64 * j]; mx = fmaxf(mx, vv[j]); }
        #pragma unroll
        for (int off = 32; off > 0; off >>= 1) mx = fmaxf(mx, __shfl_down(mx, off));
        mx = __shfl(mx, 0);
        #pragma unroll
        for (int j = 0; j < 16; ++j)
            ews[z * 1024 + lane + 64 * j] = f2bf(expf(vv[j] - mx));
    }
    const float* row = S + (size_t)l * 1024;
    float m = -1e30f;
    #pragma unroll
    for (int k = 0; k < 4; ++k) m = fmaxf(m, row[tid + 256 * k]);
    red[tid] = m; __syncthreads();          // also publishes ews
    for (int s = 128; s > 0; s >>= 1) {
        if (tid < s) red[tid] = fmaxf(red[tid], red[tid + s]);
        __syncthreads();
    }
    m = red[0];
    float ev[16];
    #pragma unroll
    for (int j = 0; j < 16; ++j) ev[j] = expf(row[lane + 64 * j] - m);
    u16* gr = Gb + (size_t)l * NN_ * 1024;
    for (int z = wv; z < NN_; z += 4) {
        const u16* er = &ews[z * 1024];
        float s = 0.f;
        #pragma unroll
        for (int j = 0; j < 16; ++j) {
            float pv = ev[j] * bf2f(er[lane + 64 * j]);
            gr[(size_t)z * 1024 + lane + 64 * j] = f2bf(pv);
            s += pv;
        }
        #pragma unroll
        for (int off = 32; off > 0; off >>= 1) s += __shfl_down(s, off);
        if (lane == 0) Z[l * NN_ + z] = s;
    }
}

// x1 = LN1(node + Pb + co); Pb is bf16 attn-out already scaled by 1/Z.
__global__ __launch_bounds__(256) void kern_ln1(
    const float* __restrict__ img, const float* __restrict__ word,
    const u16* __restrict__ Pb,
    const float* __restrict__ co, const float* __restrict__ g,
    const float* __restrict__ bta, u16* __restrict__ Xb)
{
    __shared__ float buf[DD_];
    __shared__ float red[256];
    __shared__ float stats[2];
    int row = blockIdx.x;
    int b = row / NN_, n = row - b * NN_;
    const u16* pr = Pb + (size_t)row * DD_;
    const float* cr = co + n * DD_;
    float s = 0.f;
    for (int d = threadIdx.x; d < DD_; d += 256) {
        float v = (d < IMG_) ? img[(size_t)b * IMG_ + d] : word[n * TXT_ + d - IMG_];
        v += bf2f(pr[d]) + cr[d];
        buf[d] = v; s += v;
    }
    red[threadIdx.x] = s; __syncthreads();
    for (int t = 128; t > 0; t >>= 1) {
        if (threadIdx.x < t) red[threadIdx.x] += red[threadIdx.x + t];
        __syncthreads();
    }
    if (threadIdx.x == 0) stats[0] = red[0] / DD_;
    __syncthreads();
    float mu = stats[0], s2 = 0.f;
    for (int d = threadIdx.x; d < DD_; d += 256) { float t = buf[d] - mu; s2 += t * t; }
    red[threadIdx.x] = s2; __syncthreads();
    for (int t = 128; t > 0; t >>= 1) {
        if (threadIdx.x < t) red[threadIdx.x] += red[threadIdx.x + t];
        __syncthreads();
    }
    if (threadIdx.x == 0) stats[1] = rsqrtf(red[0] / DD_ + 1e-5f);
    __syncthreads();
    float rstd = stats[1];
    u16* xb = Xb + (size_t)row * KP_;
    for (int d = threadIdx.x; d < DD_; d += 256)
        xb[d] = f2bf((buf[d] - mu) * rstd * g[d] + bta[d]);
    for (int d = DD_ + threadIdx.x; d < KP_; d += 256) xb[d] = 0;
}

// ---------------------------------------------------------------------------
// Fused LN2 + GCN1 + GCN2 + mean-pool + linear. One block per image b.
// ---------------------------------------------------------------------------
#define X2S_ 840
#define G1S_ 136
__global__ __launch_bounds__(256, 4)
void kern_gcn(const u16* __restrict__ Yb,
              const float* __restrict__ g2v, const float* __restrict__ bt2,
              const u16* __restrict__ Wg1T, const float* __restrict__ bg1,
              const u16* __restrict__ Wg2T, const float* __restrict__ bg2,
              const float* __restrict__ Wl,  const float* __restrict__ bl,
              const float* __restrict__ AdjW, float* __restrict__ out)
{
    __shared__ __align__(16) u16 x2s[16 * X2S_];      // 26.9 KB; g1s overlays
    __shared__ __align__(16) float h1s[16 * 132];     // 8.4 KB
    __shared__ float adj_s[NN_ * NN_];
    __shared__ float colw_s[16];
    __shared__ float pool_s[HID_];
    u16* g1s = x2s;                                   // overlay (16*G1S_ u16)
    const int b = blockIdx.x, tid = threadIdx.x;
    const int lane = tid & 63, wv = tid >> 6;
    const int fr = lane & 15, qd = lane >> 4;

    if (tid < NN_ * NN_) adj_s[tid] = AdjW[tid];
    if (tid >= NN_ * NN_ && tid < NN_ * NN_ + 16) colw_s[tid - NN_ * NN_] = AdjW[tid];
    for (int k = tid; k < 2 * X2S_; k += 256) x2s[14 * X2S_ + k] = 0;
    for (int k = tid; k < 14 * (X2S_ - DD_); k += 256) {
        int j = k / (X2S_ - DD_), c = k - j * (X2S_ - DD_);
        x2s[j * X2S_ + DD_ + c] = 0;
    }

    // --- LN2 per node row ---
    for (int j = wv; j < NN_; j += 4) {
        const u16* yr = Yb + (size_t)(b * NN_ + j) * KP_;
        float vv[13], s = 0.f;
        #pragma unroll
        for (int k = 0; k < 13; ++k) {
            int d = lane + 64 * k;
            float v = (d < DD_) ? bf2f(yr[d]) : 0.f;
            vv[k] = v; s += v;
        }
        #pragma unroll
        for (int off = 32; off > 0; off >>= 1) s += __shfl_down(s, off);
        s = __shfl(s, 0);
        float mu = s / (float)DD_, s2 = 0.f;
        #pragma unroll
        for (int k = 0; k < 13; ++k) {
            int d = lane + 64 * k;
            float t = (d < DD_) ? vv[k] - mu : 0.f;
            s2 += t * t;
        }
        #pragma unroll
        for (int off = 32; off > 0; off >>= 1) s2 += __shfl_down(s2, off);
        s2 = __shfl(s2, 0);
        float rstd = rsqrtf(s2 / (float)DD_ + 1e-5f);
        #pragma unroll
        for (int k = 0; k < 13; ++k) {
            int d = lane + 64 * k;
            if (d < DD_)
                x2s[j * X2S_ + d] = f2bf((vv[k] - mu) * rstd * g2v[d] + bt2[d]);
        }
    }
    __syncthreads();

    // --- GCN1 (MFMA, M=16, K=KP_) ---
    {
        f32x4 acc[2] = {{}, {}};
        const u16* wp0 = Wg1T + (size_t)(wv * 32 + fr) * KP_ + qd * 8;
        const u16* wp1 = wp0 + (size_t)16 * KP_;
        bf16x8 bc0 = *(const bf16x8*)wp0;
        bf16x8 bc1 = *(const bf16x8*)wp1;
        for (int k0 = 0; k0 < KP_; k0 += 32) {
            bf16x8 bn0 = bc0, bn1 = bc1;
            if (k0 + 32 < KP_) {
                bn0 = *(const bf16x8*)(wp0 + k0 + 32);
                bn1 = *(const bf16x8*)(wp1 + k0 + 32);
            }
            bf16x8 af = *(const bf16x8*)&x2s[fr * X2S_ + k0 + qd * 8];
            acc[0] = __builtin_amdgcn_mfma_f32_16x16x32_bf16(af, bc0, acc[0], 0, 0, 0);
            acc[1] = __builtin_amdgcn_mfma_f32_16x16x32_bf16(af, bc1, acc[1], 0, 0, 0);
            bc0 = bn0; bc1 = bn1;
        }
        #pragma unroll
        for (int t = 0; t < 2; ++t)
            #pragma unroll
            for (int i = 0; i < 4; ++i)
                h1s[(qd * 4 + i) * 132 + wv * 32 + t * 16 + fr] = acc[t][i];
    }
    __syncthreads();   // x2s dead; g1s overlay now writable

    // --- G1 = relu(Adj @ H1 + bg1) -> bf16; zero pad rows 14,15 ---
    {
        const int f = tid & 127, jj = (tid >> 7) * 7;
        #pragma unroll
        for (int j = 0; j < 7; ++j) {
            float s = bg1[f];
            #pragma unroll
            for (int i = 0; i < NN_; ++i)
                s = fmaf(adj_s[(jj + j) * NN_ + i], h1s[i * 132 + f], s);
            g1s[(jj + j) * G1S_ + f] = f2bf(s > 0.f ? s : 0.f);
        }
        for (int k = tid; k < 2 * G1S_; k += 256) g1s[14 * G1S_ + k] = 0;
    }
    __syncthreads();

    // --- GCN2 (MFMA, K=128) + pool = relu(colw·H2 + bg2) ---
    {
        f32x4 acc[2] = {{}, {}};
        const u16* wp0 = Wg2T + (size_t)(wv * 32 + fr) * HID_ + qd * 8;
        const u16* wp1 = wp0 + (size_t)16 * HID_;
        bf16x8 bc0 = *(const bf16x8*)wp0;
        bf16x8 bc1 = *(const bf16x8*)wp1;
        for (int k0 = 0; k0 < HID_; k0 += 32) {
            bf16x8 bn0 = bc0, bn1 = bc1;
            if (k0 + 32 < HID_) {
                bn0 = *(const bf16x8*)(wp0 + k0 + 32);
                bn1 = *(const bf16x8*)(wp1 + k0 + 32);
            }
            bf16x8 af = *(const bf16x8*)&g1s[fr * G1S_ + k0 + qd * 8];
            acc[0] = __builtin_amdgcn_mfma_f32_16x16x32_bf16(af, bc0, acc[0], 0, 0, 0);
            acc[1] = __builtin_amdgcn_mfma_f32_16x16x32_bf16(af, bc1, acc[1], 0, 0, 0);
            bc0 = bn0; bc1 = bn1;
        }
        #pragma unroll
        for (int t = 0; t < 2; ++t) {
            float s = 0.f;
            #pragma unroll
            for (int i = 0; i < 4; ++i) s += colw_s[qd * 4 + i] * acc[t][i];
            s += __shfl_xor(s, 16);
            s += __shfl_xor(s, 32);
            if (qd == 0) {
                int f = wv * 32 + t * 16 + fr;
                float p = s + bg2[f];
                pool_s[f] = p > 0.f ? p : 0.f;
            }
        }
    }
    __syncthreads();

    // --- out = pool @ Wl + bl ---
    if (tid < CC_) {
        float s = bl[tid];
        #pragma unroll 8
        for (int f = 0; f < HID_; ++f)
            s = fmaf(pool_s[f], Wl[(size_t)f * CC_ + tid], s);
        out[(size_t)b * CC_ + tid] = s;
    }
}

extern "C" void kernel_launch(void* const* d_in, const int* in_sizes, int n_in,
                              void* d_out, int out_size, void* d_ws, size_t ws_size,
                              hipStream_t stream)
{
    const float* img  = (const float*)d_in[0];
    const float* word = (const float*)d_in[1];
    const int*   ei   = (const int*)d_in[2];
    const float* Wi   = (const float*)d_in[3];
    const float* bi   = (const float*)d_in[4];
    const float* Wo   = (const float*)d_in[5];
    const float* bo   = (const float*)d_in[6];
    const float* g1   = (const float*)d_in[7];
    const float* bt1  = (const float*)d_in[8];
    const float* g2   = (const float*)d_in[9];
    const float* bt2  = (const float*)d_in[10];
    const float* W1   = (const float*)d_in[11];
    const float* bf1  = (const float*)d_in[12];
    const float* W2   = (const float*)d_in[13];
    const float* bf2  = (const float*)d_in[14];
    const float* Wg1  = (const float*)d_in[15];
    const float* bg1  = (const float*)d_in[16];
    const float* Wg2  = (const float*)d_in[17];
    const float* bg2  = (const float*)d_in[18];
    const float* Wl   = (const float*)d_in[19];
    const float* bl   = (const float*)d_in[20];
    float* out = (float*)d_out;

    char* ws = (char*)d_ws;
    u16*   imgb = (u16*)  (ws + OFF_IMGB);
    u16*   Wib  = (u16*)  (ws + OFF_WIB);
    u16*   wordb= (u16*)  (ws + OFF_WORDB);
    u16*   WiTX = (u16*)  (ws + OFF_WITX);
    u16*   Gb   = (u16*)  (ws + OFF_GB);
    float* Ebuf = (float*)(ws + OFF_EBUF);
    u16*   AvoT = (u16*)  (ws + OFF_AVOT);
    u16*   Wob  = (u16*)  (ws + OFF_WOB);
    u16*   Hb   = (u16*)  (ws + OFF_HB);
    u16*   Pb   = (u16*)  (ws + OFF_PB);
    u16*   X1b  = (u16*)  (ws + OFF_X1B);
    u16*   Yb   = (u16*)  (ws + OFF_YB);
    u16*   W1T  = (u16*)  (ws + OFF_W1T);
    u16*   W2T  = (u16*)  (ws + OFF_W2T);
    u16*   Aqb  = (u16*)  (ws + OFF_AQB);
    u16*   Akb  = Aqb + AROWS_ * KP_;
    u16*   Avb  = Aqb + 2 * AROWS_ * KP_;
    u16*   Tvb  = (u16*)  (ws + OFF_TVB);
    float* co   = (float*)(ws + OFF_CO);
    float* Zb   = (float*)(ws + OFF_Z);
    float* Adj  = (float*)(ws + OFF_ADJ);
    u16*   Wg1T = (u16*)  (ws + OFF_WG1T);
    u16*   Wg2T = (u16*)  (ws + OFF_WG2T);

    const float scl = 1.0f / sqrtf((float)DD_);

    // --- launch 1: multi-cast (input casts + all K-pad zeroing) ---
    {
        CPack p; p.n = 9;
        unsigned c = 0;
        auto seg = [&](int i, const float* s, int srs, u16* d, int drs,
                       int rows, int dcols, int scols) {
            p.d[i] = { s, d, srs, drs, dcols, scols };
            p.cum[i] = c; c += (unsigned)rows * dcols;
        };
        seg(0, img,        IMG_, imgb,  IMG_, B_,   IMG_, IMG_);
        seg(1, Wi,         DD_,  Wib,   IMG_, D3_,  IMG_, IMG_);
        seg(2, word,       TXT_, wordb, TXP_, NN_,  TXP_, TXT_);
        seg(3, Wi + IMG_,  DD_,  WiTX,  TXP_, D3_,  TXP_, TXT_);
        seg(4, Wo,         DD_,  Wob,   KP_,  DD_,  KP_,  DD_);
        seg(5, nullptr, 0, Aqb + DD_,                    KP_, 1038, 20, 0); // Aq + Tq rows
        seg(6, nullptr, 0, Aqb + AROWS_ * KP_ + DD_,     KP_, 1024, 20, 0);
        seg(7, nullptr, 0, Aqb + 2 * AROWS_ * KP_ + DD_, KP_, 1024, 20, 0);
        seg(8, nullptr, 0, Tvb + DD_,                    KP_, NN_,  20, 0); // Tvb pads
        p.cum[9] = c;
        kern_mcast<<<(c + 255) / 256, 256, 0, stream>>>(p);
    }

    // --- launch 2 (mix1): T epi8 + A-proj || Wg1T/Wg2T transposes || adj ---
    {
        MPack p{};
        p.ng = 2; p.gtot = 180;
        p.g[0] = { wordb, WiTX, (float*)Tvb, Aqb, bi,
                   TXP_, TXP_, 0, 0, NN_, D3_, TXP_, 8, 20, 0, 0, 1.f };
        p.g[1] = { imgb, Wib, nullptr, Aqb, nullptr,
                   IMG_, IMG_, 0, 0, B_, D3_, IMG_, 4, 20, 1, 20, 1.f };
        p.nt = 2;
        p.t[0] = { Wg1, Wg1T, HID_, KP_,  DD_,  HID_, KP_,  26, 26 * 4 };
        p.t[1] = { Wg2, Wg2T, HID_, HID_, HID_, HID_, HID_, 4,  4 * 4 };
        p.ei = ei; p.Adj = Adj;
        kern_mix<<<180 + 104 + 16 + 1, 512, 0, stream>>>(p);
    }

    // --- launch 3 (mix2): S0+w || AvoT || co  ||  W1T/W2T transposes ---
    {
        MPack p{};
        p.ng = 3; p.gtot = 135;
        p.g[0] = { Aqb, Akb, Ebuf, nullptr, nullptr,
                   KP_, KP_, 1024, 0, 1024 + NN_, 1024, KP_, 0, 8, 0, 0, scl };
        p.g[1] = { Wob, Avb, nullptr, AvoT, nullptr,
                   KP_, KP_, 0, 1024, DD_, B_, KP_, 3, 8, 0, 72, 1.f };
        p.g[2] = { Tvb, Wob, co, nullptr, bo,
                   KP_, KP_, DD_, 0, NN_, DD_, KP_, 6, 7, 0, 128, 1.f };
        p.nt = 2;
        p.t[0] = { W1, W1T, FF_, KP_, DD_, FF_, KP_, 26, 26 * 64 };
        p.t[1] = { W2, W2T, DD_, FF_, FF_, DD_, FF_, 64, 64 * 26 };
        p.ei = nullptr; p.Adj = nullptr;
        kern_mix<<<135 + 1664 + 1664, 512, 0, stream>>>(p);
    }

    // --- launch 4: fused ew-exp + exp + G + Z ---
    kern_eG<<<1024, 256, 0, stream>>>(Ebuf, Gb, Zb);

    // --- launch 5: Pb = (G @ Avo)/Z as bf16 (4-wave body) ---
    bgemm<5><<<7 * 112, 256, 0, stream>>>(Gb, 1024, AvoT, 1024,
        BNR_, DD_, 1024, 1.f, nullptr, 0, Pb, DD_, Zb, 7, 1);

    // --- launch 6: LN1 ---
    kern_ln1<<<BNR_, 256, 0, stream>>>(img, word, Pb, co, g1, bt1, X1b);

    // --- launches 7,8: FFN (4-wave body — round-11 proven 96 µs) ---
    bgemm<1><<<16 * 112, 256, 0, stream>>>(X1b, KP_, W1T, KP_,
        BNR_, FF_, KP_, 1.f, nullptr, 0, Hb, FF_, bf1, 16, 1);
    bgemm<7><<<7 * 112, 256, 0, stream>>>(Hb, FF_, W2T, FF_,
        BNR_, DD_, FF_, 1.f, (float*)X1b, KP_, Yb, KP_, bf2, 7, 1);

    // --- launch 9: fused LN2 + GCN1 + GCN2 + pool + linear ---
    kern_gcn<<<B_, 256, 0, stream>>>(Yb, g2, bt2, Wg1T, bg1, Wg2T, bg2,
                                     Wl, bl, Adj, out);
}